// Round 1
// baseline (6538.313 us; speedup 1.0000x reference)
//
#include <hip/hip_runtime.h>
#include <cstdint>
#include <cstddef>

#define T_LEN 8192
#define DIMC  256
#define NBUCK 128
#define BHEAD 32   // B*H

// ---------------------------------------------------------------------------
// y[b,t,d] = x[b,d,t] + pe0[t/64,d] + pe1[t%64,d]
// block (32,8), grid (T/32, DIM/32, B)
// ---------------------------------------------------------------------------
__global__ __launch_bounds__(256)
void add_pos_k(const float* __restrict__ x, const float* __restrict__ pe0,
               const float* __restrict__ pe1, float* __restrict__ y) {
  __shared__ float tile[32][33];
  int b  = blockIdx.z;
  int t0 = blockIdx.x * 32;
  int d0 = blockIdx.y * 32;
  int tj = threadIdx.x;   // 0..31
  int di = threadIdx.y;   // 0..7
#pragma unroll
  for (int k = 0; k < 4; k++) {
    int d = d0 + di + k * 8;
    tile[di + k * 8][tj] = x[((size_t)b * DIMC + d) * T_LEN + t0 + tj];
  }
  __syncthreads();
#pragma unroll
  for (int k = 0; k < 4; k++) {
    int t = t0 + di + k * 8;
    int d = d0 + tj;
    y[((size_t)b * T_LEN + t) * DIMC + d] =
        tile[tj][di + k * 8] + pe0[(size_t)(t >> 6) * DIMC + d] + pe1[(size_t)(t & 63) * DIMC + d];
  }
}

// ---------------------------------------------------------------------------
// LayerNorm over last dim (256). One wave per row, 4 rows per block.
// ---------------------------------------------------------------------------
__global__ __launch_bounds__(256)
void layernorm_k(const float* __restrict__ x, const float* __restrict__ g,
                 const float* __restrict__ b, float* __restrict__ o) {
  int row  = blockIdx.x * 4 + (threadIdx.x >> 6);
  int lane = threadIdx.x & 63;
  const float4* xr = (const float4*)(x + (size_t)row * DIMC);
  float4 v = xr[lane];
  float s  = v.x + v.y + v.z + v.w;
  float s2 = v.x * v.x + v.y * v.y + v.z * v.z + v.w * v.w;
#pragma unroll
  for (int off = 32; off; off >>= 1) {
    s  += __shfl_xor(s, off);
    s2 += __shfl_xor(s2, off);
  }
  float mean = s * (1.0f / 256.0f);
  float var  = s2 * (1.0f / 256.0f) - mean * mean;
  float r    = rsqrtf(var + 1e-5f);
  float4 gv = ((const float4*)g)[lane];
  float4 bv = ((const float4*)b)[lane];
  float4 ov;
  ov.x = (v.x - mean) * r * gv.x + bv.x;
  ov.y = (v.y - mean) * r * gv.y + bv.y;
  ov.z = (v.z - mean) * r * gv.z + bv.z;
  ov.w = (v.w - mean) * r * gv.w + bv.w;
  ((float4*)(o + (size_t)row * DIMC))[lane] = ov;
}

// ---------------------------------------------------------------------------
// fp32 GEMM: C(MxN) = epi(A(MxK) @ B(KxN) + bias)
// EPI: 0 = store (opt bias), 1 = gelu(A@B+bias), 2 = C += A@B (+opt bias)
// 64x64 tile, BK=16, 256 threads, 4x4 per thread.
// ---------------------------------------------------------------------------
template <int EPI>
__global__ __launch_bounds__(256)
void gemm_f32(const float* __restrict__ A, const float* __restrict__ Bm,
              const float* __restrict__ bias, float* __restrict__ C,
              int M, int N, int K, int ldb) {
  __shared__ float As[16][68];
  __shared__ float Bs[16][68];
  int tid = threadIdx.x;
  int bm = blockIdx.y * 64;
  int bn = blockIdx.x * 64;
  int tx = tid & 15, ty = tid >> 4;
  float acc[4][4] = {};
  int am  = tid >> 2;          // 0..63 (row)
  int ak  = (tid & 3) << 2;    // 0,4,8,12
  int bk  = tid >> 4;          // 0..15 (k row)
  int bn4 = (tid & 15) << 2;   // 0..60
  const float* Aptr = A + (size_t)(bm + am) * K + ak;
  const float* Bptr = Bm + (size_t)bk * ldb + bn + bn4;
  for (int k0 = 0; k0 < K; k0 += 16) {
    float4 av = *(const float4*)(Aptr + k0);
    float4 bv = *(const float4*)(Bptr + (size_t)k0 * ldb);
    As[ak + 0][am] = av.x;
    As[ak + 1][am] = av.y;
    As[ak + 2][am] = av.z;
    As[ak + 3][am] = av.w;
    *(float4*)&Bs[bk][bn4] = bv;
    __syncthreads();
#pragma unroll
    for (int kk = 0; kk < 16; kk++) {
      float4 a4 = *(float4*)&As[kk][ty << 2];
      float4 b4 = *(float4*)&Bs[kk][tx << 2];
      float a[4] = {a4.x, a4.y, a4.z, a4.w};
      float bb[4] = {b4.x, b4.y, b4.z, b4.w};
#pragma unroll
      for (int i = 0; i < 4; i++)
#pragma unroll
        for (int j = 0; j < 4; j++) acc[i][j] += a[i] * bb[j];
    }
    __syncthreads();
  }
  int tx4 = tx << 2;
#pragma unroll
  for (int i = 0; i < 4; i++) {
    size_t m = (size_t)(bm + (ty << 2) + i);
    float* crow = C + m * N + bn + tx4;
    float4 v = {acc[i][0], acc[i][1], acc[i][2], acc[i][3]};
    if (bias) {
      float4 bb = *(const float4*)(bias + bn + tx4);
      v.x += bb.x; v.y += bb.y; v.z += bb.z; v.w += bb.w;
    }
    if (EPI == 1) {
      v.x = 0.5f * v.x * (1.0f + erff(v.x * 0.70710678118654752f));
      v.y = 0.5f * v.y * (1.0f + erff(v.y * 0.70710678118654752f));
      v.z = 0.5f * v.z * (1.0f + erff(v.z * 0.70710678118654752f));
      v.w = 0.5f * v.w * (1.0f + erff(v.w * 0.70710678118654752f));
    }
    if (EPI == 2) {
      float4 c0 = *(const float4*)crow;
      v.x += c0.x; v.y += c0.y; v.z += c0.z; v.w += c0.w;
    }
    *(float4*)crow = v;
  }
}

// ---------------------------------------------------------------------------
// bucket summaries: sq[bh,i,d] = mean_t q[b, i*64+t, h*32+d]; sk same from kv.
// grid BH*NB, block 64 (lanes 0..31 -> sq, 32..63 -> sk)
// ---------------------------------------------------------------------------
__global__ __launch_bounds__(64)
void summary_k(const float* __restrict__ q, const float* __restrict__ kv,
               float* __restrict__ sq, float* __restrict__ sk) {
  int blk = blockIdx.x;
  int bh = blk >> 7, ib = blk & 127;
  int b = bh >> 3, h = bh & 7;
  int lane = threadIdx.x;
  int d = lane & 31;
  bool isK = lane >= 32;
  const float* src = isK ? kv : q;
  size_t rs = isK ? 512 : 256;
  size_t base = ((size_t)b * T_LEN + (size_t)ib * 64) * rs + h * 32 + d;
  float s = 0.f;
#pragma unroll 8
  for (int t = 0; t < 64; t++) s += src[base + (size_t)t * rs];
  s *= (1.0f / 64.0f);
  float* dst = isK ? sk : sq;
  dst[((size_t)bh * NBUCK + ib) * 32 + d] = s;
}

// ---------------------------------------------------------------------------
// routing: per (bh,i): logits L_j = dot(sq_i, sk_j)*dh^-0.5/0.75 over j=0..127
// idx = argmax (first-index tie-break, matches jnp.argmax); w = softmax max = 1/Z
// grid BH*NB, block 64 (each lane handles j=lane, j=lane+64)
// ---------------------------------------------------------------------------
__global__ __launch_bounds__(64)
void route_k(const float* __restrict__ sq, const float* __restrict__ sk,
             int* __restrict__ ridx, float* __restrict__ rw) {
  int blk = blockIdx.x;
  int bh = blk >> 7, ib = blk & 127;
  int lane = threadIdx.x;
  const float* qrow = sq + ((size_t)bh * NBUCK + ib) * 32;
  const float* k0 = sk + ((size_t)bh * NBUCK + lane) * 32;
  const float* k1 = k0 + 64 * 32;
  float s0 = 0.f, s1 = 0.f;
#pragma unroll
  for (int d = 0; d < 32; d++) {
    float qd = qrow[d];
    s0 += qd * k0[d];
    s1 += qd * k1[d];
  }
  const float sc = 0.17677669529663687f * (4.0f / 3.0f);  // dh^-0.5 / 0.75
  float L0 = s0 * sc, L1 = s1 * sc;
  float m = fmaxf(L0, L1);
#pragma unroll
  for (int off = 32; off; off >>= 1) m = fmaxf(m, __shfl_xor(m, off));
  float Z = expf(L0 - m) + expf(L1 - m);
#pragma unroll
  for (int off = 32; off; off >>= 1) Z += __shfl_xor(Z, off);
  // argmax with lowest-index tie-break
  float mv = (L1 > L0) ? L1 : L0;
  int mj = (L1 > L0) ? lane + 64 : lane;
#pragma unroll
  for (int off = 32; off; off >>= 1) {
    float ov = __shfl_xor(mv, off);
    int oj = __shfl_xor(mj, off);
    if (ov > mv || (ov == mv && oj < mj)) { mv = ov; mj = oj; }
  }
  if (lane == 0) {
    ridx[blk] = mj;
    rw[blk] = 1.0f / Z;   // exp(Lmax - m)/Z with m == Lmax
  }
}

// ---------------------------------------------------------------------------
// bucketed attention. grid BH*NB, block 256.
// K/V = [w * bucket(jr) ; bucket(ib)] staged in LDS (128x32, pad 36).
// thread: t = tid>>2, sub = tid&3 owns u = sub*32..sub*32+31.
// ---------------------------------------------------------------------------
__global__ __launch_bounds__(256)
void attn_k(const float* __restrict__ q, const float* __restrict__ kv,
            const int* __restrict__ ridx, const float* __restrict__ rw,
            float* __restrict__ o) {
  __shared__ float ks[128][36];
  __shared__ float vs[128][36];
  int blk = blockIdx.x;
  int bh = blk >> 7, ib = blk & 127;
  int b = bh >> 3, h = bh & 7;
  int tid = threadIdx.x;
  int jr = ridx[blk];
  float w = rw[blk];
  // stage K/V
  {
    int d = tid & 31, r0 = tid >> 5;
    size_t baseR = ((size_t)b * T_LEN + (size_t)jr * 64) * 512 + h * 32 + d;
    size_t baseO = ((size_t)b * T_LEN + (size_t)ib * 64) * 512 + h * 32 + d;
#pragma unroll
    for (int p = 0; p < 8; p++) {
      int r = r0 + p * 8;
      ks[r][d]      = w * kv[baseR + (size_t)r * 512];
      ks[r + 64][d] =     kv[baseO + (size_t)r * 512];
      vs[r][d]      = w * kv[baseR + (size_t)r * 512 + 256];
      vs[r + 64][d] =     kv[baseO + (size_t)r * 512 + 256];
    }
  }
  int t = tid >> 2, sub = tid & 3;
  // q row into registers
  float4 qreg[8];
  const float* qrow = q + ((size_t)b * T_LEN + (size_t)ib * 64 + t) * DIMC + h * 32;
#pragma unroll
  for (int c = 0; c < 8; c++) qreg[c] = *(const float4*)(qrow + c * 4);
  __syncthreads();
  // scores for u = sub*32 + j
  float scv[32];
#pragma unroll 4
  for (int j = 0; j < 32; j++) {
    int u = sub * 32 + j;
    float s = 0.f;
#pragma unroll
    for (int c = 0; c < 8; c++) {
      float4 k4 = *(float4*)&ks[u][c * 4];
      s += qreg[c].x * k4.x + qreg[c].y * k4.y + qreg[c].z * k4.z + qreg[c].w * k4.w;
    }
    scv[j] = s * 0.17677669529663687f;
  }
  // softmax across the 4 lanes of this row
  float m = -1e30f;
#pragma unroll
  for (int j = 0; j < 32; j++) m = fmaxf(m, scv[j]);
  m = fmaxf(m, __shfl_xor(m, 1));
  m = fmaxf(m, __shfl_xor(m, 2));
  float sum = 0.f;
#pragma unroll
  for (int j = 0; j < 32; j++) {
    scv[j] = expf(scv[j] - m);
    sum += scv[j];
  }
  sum += __shfl_xor(sum, 1);
  sum += __shfl_xor(sum, 2);
  float inv = 1.0f / sum;
#pragma unroll
  for (int j = 0; j < 32; j++) scv[j] *= inv;
  // PV
  float outv[32];
#pragma unroll
  for (int i = 0; i < 32; i++) outv[i] = 0.f;
#pragma unroll 4
  for (int j = 0; j < 32; j++) {
    int u = sub * 32 + j;
    float pv = scv[j];
#pragma unroll
    for (int c = 0; c < 8; c++) {
      float4 v4 = *(float4*)&vs[u][c * 4];
      outv[c * 4 + 0] += pv * v4.x;
      outv[c * 4 + 1] += pv * v4.y;
      outv[c * 4 + 2] += pv * v4.z;
      outv[c * 4 + 3] += pv * v4.w;
    }
  }
#pragma unroll
  for (int i = 0; i < 32; i++) {
    outv[i] += __shfl_xor(outv[i], 1);
    outv[i] += __shfl_xor(outv[i], 2);
  }
  float* orow = o + ((size_t)b * T_LEN + (size_t)ib * 64 + t) * DIMC + h * 32;
  float4 w0 = {outv[sub * 8 + 0], outv[sub * 8 + 1], outv[sub * 8 + 2], outv[sub * 8 + 3]};
  float4 w1 = {outv[sub * 8 + 4], outv[sub * 8 + 5], outv[sub * 8 + 6], outv[sub * 8 + 7]};
  *(float4*)(orow + sub * 8) = w0;
  *(float4*)(orow + sub * 8 + 4) = w1;
}

// ---------------------------------------------------------------------------
// out[b,d,t] = yln[b,t,d]
// ---------------------------------------------------------------------------
__global__ __launch_bounds__(256)
void transpose_out_k(const float* __restrict__ yln, float* __restrict__ out) {
  __shared__ float tile[32][33];
  int b  = blockIdx.z;
  int t0 = blockIdx.x * 32;
  int d0 = blockIdx.y * 32;
  int tx = threadIdx.x;  // 0..31
  int ty = threadIdx.y;  // 0..7
#pragma unroll
  for (int k = 0; k < 4; k++) {
    int t = t0 + ty + k * 8;
    tile[ty + k * 8][tx] = yln[((size_t)b * T_LEN + t) * DIMC + d0 + tx];
  }
  __syncthreads();
#pragma unroll
  for (int k = 0; k < 4; k++) {
    int d = d0 + ty + k * 8;
    out[((size_t)b * DIMC + d) * T_LEN + t0 + tx] = tile[tx][ty + k * 8];
  }
}

// ---------------------------------------------------------------------------
extern "C" void kernel_launch(void* const* d_in, const int* in_sizes, int n_in,
                              void* d_out, int out_size, void* d_ws, size_t ws_size,
                              hipStream_t stream) {
  const float* x     = (const float*)d_in[0];
  const float* pe0   = (const float*)d_in[1];
  const float* pe1   = (const float*)d_in[2];
  const float* ln1_g = (const float*)d_in[3];
  const float* ln1_b = (const float*)d_in[4];
  const float* Wq    = (const float*)d_in[5];
  const float* Wkv   = (const float*)d_in[6];
  const float* Wo    = (const float*)d_in[7];
  const float* bo    = (const float*)d_in[8];
  const float* ln2_g = (const float*)d_in[9];
  const float* ln2_b = (const float*)d_in[10];
  const float* W1    = (const float*)d_in[11];
  const float* b1    = (const float*)d_in[12];
  const float* W2    = (const float*)d_in[13];
  const float* b2    = (const float*)d_in[14];
  const float* gf    = (const float*)d_in[15];
  const float* bfp   = (const float*)d_in[16];
  float* out = (float*)d_out;

  const int M = 4 * T_LEN;  // 32768
  // workspace layout (floats)
  float* y   = (float*)d_ws;            // M*256
  float* h   = y + (size_t)M * 256;     // M*256  (LN out, then attn out, then LN2 out)
  float* qb  = h + (size_t)M * 256;     // M*256
  float* kvb = qb + (size_t)M * 256;    // M*512  (kv, later FF half intermediate)
  float* sqb = kvb + (size_t)M * 512;   // 32*128*32
  float* skb = sqb + 32 * 128 * 32;
  float* rwb = skb + 32 * 128 * 32;     // 4096
  int*   rib = (int*)(rwb + 4096);      // 4096

  dim3 tb(32, 8);
  add_pos_k<<<dim3(T_LEN / 32, DIMC / 32, 4), tb, 0, stream>>>(x, pe0, pe1, y);

  for (int l = 0; l < 6; l++) {
    const float* wq  = Wq  + (size_t)l * 256 * 256;
    const float* wkv = Wkv + (size_t)l * 256 * 512;
    const float* wo  = Wo  + (size_t)l * 256 * 256;
    const float* w1  = W1  + (size_t)l * 256 * 1024;
    const float* w2  = W2  + (size_t)l * 1024 * 256;

    layernorm_k<<<M / 4, 256, 0, stream>>>(y, ln1_g + l * 256, ln1_b + l * 256, h);
    gemm_f32<0><<<dim3(256 / 64, M / 64), 256, 0, stream>>>(h, wq, nullptr, qb, M, 256, 256, 256);
    gemm_f32<0><<<dim3(512 / 64, M / 64), 256, 0, stream>>>(h, wkv, nullptr, kvb, M, 512, 256, 512);
    summary_k<<<BHEAD * NBUCK, 64, 0, stream>>>(qb, kvb, sqb, skb);
    route_k<<<BHEAD * NBUCK, 64, 0, stream>>>(sqb, skb, rib, rwb);
    attn_k<<<BHEAD * NBUCK, 256, 0, stream>>>(qb, kvb, rib, rwb, h);
    gemm_f32<2><<<dim3(256 / 64, M / 64), 256, 0, stream>>>(h, wo, bo + l * 256, y, M, 256, 256, 256);
    layernorm_k<<<M / 4, 256, 0, stream>>>(y, ln2_g + l * 256, ln2_b + l * 256, h);
    // FF in two 512-wide halves; intermediate reuses kv buffer
    gemm_f32<1><<<dim3(512 / 64, M / 64), 256, 0, stream>>>(h, w1, b1 + l * 1024, kvb, M, 512, 256, 1024);
    gemm_f32<2><<<dim3(256 / 64, M / 64), 256, 0, stream>>>(kvb, w2, b2 + l * 256, y, M, 256, 512, 256);
    gemm_f32<1><<<dim3(512 / 64, M / 64), 256, 0, stream>>>(h, w1 + 512, b1 + l * 1024 + 512, kvb, M, 512, 256, 1024);
    gemm_f32<2><<<dim3(256 / 64, M / 64), 256, 0, stream>>>(kvb, w2 + (size_t)512 * 256, nullptr, y, M, 256, 512, 256);
  }

  layernorm_k<<<M / 4, 256, 0, stream>>>(y, gf, bfp, h);
  transpose_out_k<<<dim3(T_LEN / 32, DIMC / 32, 4), tb, 0, stream>>>(h, out);

  (void)in_sizes; (void)n_in; (void)out_size; (void)ws_size;
}

// Round 2
// 2097.756 us; speedup vs baseline: 3.1168x; 3.1168x over previous
//
#include <hip/hip_runtime.h>
#include <cstdint>
#include <cstddef>

#define T_LEN 8192
#define DIMC  256
#define NBUCK 128
#define BHEAD 32
#define MROWS 32768

typedef __attribute__((ext_vector_type(8))) short bf16x8;
typedef __attribute__((ext_vector_type(4))) float f32x4;

__device__ __forceinline__ ushort f2bf(float x) {
  union { float f; unsigned u; } v; v.f = x;
  unsigned r = v.u + 0x7fffu + ((v.u >> 16) & 1u);
  return (ushort)(r >> 16);
}

__device__ __forceinline__ void gld16(const void* g, void* l) {
  __builtin_amdgcn_global_load_lds((const __attribute__((address_space(1))) void*)g,
                                   (__attribute__((address_space(3))) void*)l, 16, 0, 0);
}

// ---------------------------------------------------------------------------
// y[b,t,d] = x[b,d,t] + pe0[t/64,d] + pe1[t%64,d]
// ---------------------------------------------------------------------------
__global__ __launch_bounds__(256)
void add_pos_k(const float* __restrict__ x, const float* __restrict__ pe0,
               const float* __restrict__ pe1, float* __restrict__ y) {
  __shared__ float tile[32][33];
  int b  = blockIdx.z;
  int t0 = blockIdx.x * 32;
  int d0 = blockIdx.y * 32;
  int tj = threadIdx.x;
  int di = threadIdx.y;
#pragma unroll
  for (int k = 0; k < 4; k++) {
    int d = d0 + di + k * 8;
    tile[di + k * 8][tj] = x[((size_t)b * DIMC + d) * T_LEN + t0 + tj];
  }
  __syncthreads();
#pragma unroll
  for (int k = 0; k < 4; k++) {
    int t = t0 + di + k * 8;
    int d = d0 + tj;
    y[((size_t)b * T_LEN + t) * DIMC + d] =
        tile[tj][di + k * 8] + pe0[(size_t)(t >> 6) * DIMC + d] + pe1[(size_t)(t & 63) * DIMC + d];
  }
}

// ---------------------------------------------------------------------------
// LayerNorm over last dim (256). One wave per row, 4 rows per block.
// BF=1: write bf16 (ushort), BF=0: write fp32.
// ---------------------------------------------------------------------------
template <int BF>
__global__ __launch_bounds__(256)
void layernorm_k(const float* __restrict__ x, const float* __restrict__ g,
                 const float* __restrict__ b, void* __restrict__ o) {
  int row  = blockIdx.x * 4 + (threadIdx.x >> 6);
  int lane = threadIdx.x & 63;
  const float4* xr = (const float4*)(x + (size_t)row * DIMC);
  float4 v = xr[lane];
  float s  = v.x + v.y + v.z + v.w;
  float s2 = v.x * v.x + v.y * v.y + v.z * v.z + v.w * v.w;
#pragma unroll
  for (int off = 32; off; off >>= 1) {
    s  += __shfl_xor(s, off);
    s2 += __shfl_xor(s2, off);
  }
  float mean = s * (1.0f / 256.0f);
  float var  = s2 * (1.0f / 256.0f) - mean * mean;
  float r    = rsqrtf(var + 1e-5f);
  float4 gv = ((const float4*)g)[lane];
  float4 bv = ((const float4*)b)[lane];
  float4 ov;
  ov.x = (v.x - mean) * r * gv.x + bv.x;
  ov.y = (v.y - mean) * r * gv.y + bv.y;
  ov.z = (v.z - mean) * r * gv.z + bv.z;
  ov.w = (v.w - mean) * r * gv.w + bv.w;
  if (BF) {
    ushort4 o4;
    o4.x = f2bf(ov.x); o4.y = f2bf(ov.y); o4.z = f2bf(ov.z); o4.w = f2bf(ov.w);
    ((ushort4*)((ushort*)o + (size_t)row * DIMC))[lane] = o4;
  } else {
    ((float4*)((float*)o + (size_t)row * DIMC))[lane] = ov;
  }
}

// ---------------------------------------------------------------------------
// weight convert: Wt[l][n][k] = bf16(W[l][k][n])
// block (32,8), grid (N/32, K/32, L). out layer stride = outStride (ushorts).
// ---------------------------------------------------------------------------
__global__ __launch_bounds__(256)
void wt_bf16_k(const float* __restrict__ W, ushort* __restrict__ Wt,
               int K, int N, size_t outStride) {
  __shared__ float t[32][33];
  int l = blockIdx.z;
  const float* Wl = W + (size_t)l * K * N;
  ushort* Wtl = Wt + (size_t)l * outStride;
  int n0 = blockIdx.x * 32, k0 = blockIdx.y * 32;
  int tx = threadIdx.x, ty = threadIdx.y;
#pragma unroll
  for (int p = 0; p < 4; p++)
    t[ty + p * 8][tx] = Wl[(size_t)(k0 + ty + p * 8) * N + n0 + tx];
  __syncthreads();
#pragma unroll
  for (int p = 0; p < 4; p++)
    Wtl[(size_t)(n0 + ty + p * 8) * K + k0 + tx] = f2bf(t[tx][ty + p * 8]);
}

// ---------------------------------------------------------------------------
// bf16 MFMA GEMM: C(MxN) = epi(A(MxK) @ Bt(NxK)^T + bias)
// EPI 0: store fp32.  EPI 1: gelu(.+bias) -> bf16 (Cbf).  EPI 2: C += . + bias (fp32).
// 128x128 tile, BK=32, 256 threads (4 waves, 2x2), 4x4 MFMA 16x16x32 per wave.
// ---------------------------------------------------------------------------
template <int EPI>
__global__ __launch_bounds__(256)
void gemm_bf16(const ushort* __restrict__ A, const ushort* __restrict__ Bt,
               const float* __restrict__ bias, float* __restrict__ C,
               ushort* __restrict__ Cbf, int N, int K) {
  __shared__ ushort As[128 * 32];
  __shared__ ushort Bs[128 * 32];
  int tid = threadIdx.x;
  int w = tid >> 6, lane = tid & 63;
  int bm = blockIdx.y << 7, bn = blockIdx.x << 7;
  int wm = (w >> 1) << 6, wn = (w & 1) << 6;
  int l15 = lane & 15, quad = lane >> 4;

  // staging geometry: wave w covers bytes [w*2048, w*2048+2048) of the 8KB tile
  int off0 = (w << 11) + (lane << 4);
  int off1 = off0 + 1024;
  int r0 = off0 >> 6, c0 = (off0 & 63) >> 1;
  int r1 = off1 >> 6, c1 = (off1 & 63) >> 1;
  const ushort* ga0 = A + (size_t)(bm + r0) * K + c0;
  const ushort* ga1 = A + (size_t)(bm + r1) * K + c1;
  const ushort* gb0 = Bt + (size_t)(bn + r0) * K + c0;
  const ushort* gb1 = Bt + (size_t)(bn + r1) * K + c1;
  ushort* lA0 = As + (w << 10);
  ushort* lA1 = lA0 + 512;
  ushort* lB0 = Bs + (w << 10);
  ushort* lB1 = lB0 + 512;

  f32x4 acc[4][4];
#pragma unroll
  for (int i = 0; i < 4; i++)
#pragma unroll
    for (int j = 0; j < 4; j++) {
      f32x4 z = {0.f, 0.f, 0.f, 0.f};
      acc[i][j] = z;
    }

  for (int k0 = 0; k0 < K; k0 += 32) {
    gld16(ga0 + k0, lA0);
    gld16(ga1 + k0, lA1);
    gld16(gb0 + k0, lB0);
    gld16(gb1 + k0, lB1);
    __syncthreads();
    bf16x8 aF[4], bF[4];
#pragma unroll
    for (int i = 0; i < 4; i++)
      aF[i] = *(const bf16x8*)(As + ((wm + (i << 4) + l15) << 5) + (quad << 3));
#pragma unroll
    for (int j = 0; j < 4; j++)
      bF[j] = *(const bf16x8*)(Bs + ((wn + (j << 4) + l15) << 5) + (quad << 3));
#pragma unroll
    for (int i = 0; i < 4; i++)
#pragma unroll
      for (int j = 0; j < 4; j++)
        acc[i][j] = __builtin_amdgcn_mfma_f32_16x16x32_bf16(aF[i], bF[j], acc[i][j], 0, 0, 0);
    __syncthreads();
  }

#pragma unroll
  for (int j = 0; j < 4; j++) {
    int col = bn + wn + (j << 4) + l15;
    float bv = bias ? bias[col] : 0.f;
#pragma unroll
    for (int i = 0; i < 4; i++) {
      int rowb = bm + wm + (i << 4) + (quad << 2);
#pragma unroll
      for (int r = 0; r < 4; r++) {
        float v = acc[i][j][r];
        size_t idx = (size_t)(rowb + r) * N + col;
        if (EPI == 0) {
          C[idx] = v;
        } else if (EPI == 1) {
          v += bv;
          v = 0.5f * v * (1.0f + erff(v * 0.70710678118654752f));
          Cbf[idx] = f2bf(v);
        } else {
          C[idx] = C[idx] + v + bv;
        }
      }
    }
  }
}

// ---------------------------------------------------------------------------
// bucket summaries (unchanged, fp32 q/kv)
// ---------------------------------------------------------------------------
__global__ __launch_bounds__(64)
void summary_k(const float* __restrict__ q, const float* __restrict__ kv,
               float* __restrict__ sq, float* __restrict__ sk) {
  int blk = blockIdx.x;
  int bh = blk >> 7, ib = blk & 127;
  int b = bh >> 3, h = bh & 7;
  int lane = threadIdx.x;
  int d = lane & 31;
  bool isK = lane >= 32;
  const float* src = isK ? kv : q;
  size_t rs = isK ? 512 : 256;
  size_t base = ((size_t)b * T_LEN + (size_t)ib * 64) * rs + h * 32 + d;
  float s = 0.f;
#pragma unroll 8
  for (int t = 0; t < 64; t++) s += src[base + (size_t)t * rs];
  s *= (1.0f / 64.0f);
  float* dst = isK ? sk : sq;
  dst[((size_t)bh * NBUCK + ib) * 32 + d] = s;
}

// ---------------------------------------------------------------------------
// routing (unchanged)
// ---------------------------------------------------------------------------
__global__ __launch_bounds__(64)
void route_k(const float* __restrict__ sq, const float* __restrict__ sk,
             int* __restrict__ ridx, float* __restrict__ rw) {
  int blk = blockIdx.x;
  int bh = blk >> 7, ib = blk & 127;
  int lane = threadIdx.x;
  const float* qrow = sq + ((size_t)bh * NBUCK + ib) * 32;
  const float* k0 = sk + ((size_t)bh * NBUCK + lane) * 32;
  const float* k1 = k0 + 64 * 32;
  float s0 = 0.f, s1 = 0.f;
#pragma unroll
  for (int d = 0; d < 32; d++) {
    float qd = qrow[d];
    s0 += qd * k0[d];
    s1 += qd * k1[d];
  }
  const float sc = 0.17677669529663687f * (4.0f / 3.0f);
  float L0 = s0 * sc, L1 = s1 * sc;
  float m = fmaxf(L0, L1);
#pragma unroll
  for (int off = 32; off; off >>= 1) m = fmaxf(m, __shfl_xor(m, off));
  float Z = expf(L0 - m) + expf(L1 - m);
#pragma unroll
  for (int off = 32; off; off >>= 1) Z += __shfl_xor(Z, off);
  float mv = (L1 > L0) ? L1 : L0;
  int mj = (L1 > L0) ? lane + 64 : lane;
#pragma unroll
  for (int off = 32; off; off >>= 1) {
    float ov = __shfl_xor(mv, off);
    int oj = __shfl_xor(mj, off);
    if (ov > mv || (ov == mv && oj < mj)) { mv = ov; mj = oj; }
  }
  if (lane == 0) {
    ridx[blk] = mj;
    rw[blk] = 1.0f / Z;
  }
}

// ---------------------------------------------------------------------------
// bucketed attention. u = j*4 + sub interleave -> conflict-free LDS reads.
// Output written as bf16 into hbf.
// ---------------------------------------------------------------------------
__global__ __launch_bounds__(256)
void attn_k(const float* __restrict__ q, const float* __restrict__ kv,
            const int* __restrict__ ridx, const float* __restrict__ rw,
            ushort* __restrict__ o) {
  __shared__ float ks[128][36];
  __shared__ float vs[128][36];
  int blk = blockIdx.x;
  int bh = blk >> 7, ib = blk & 127;
  int b = bh >> 3, h = bh & 7;
  int tid = threadIdx.x;
  int jr = ridx[blk];
  float w = rw[blk];
  // stage K/V (float4, rows 0..63 routed*w, 64..127 own)
  {
    int c4 = (tid & 7) * 4, rr = tid >> 3;
#pragma unroll
    for (int p = 0; p < 4; p++) {
      int row = rr + p * 32;
      int srcb = row < 64 ? jr : ib;
      int tt   = row < 64 ? row : row - 64;
      float sc = row < 64 ? w : 1.f;
      const float* kp = kv + ((size_t)b * T_LEN + (size_t)srcb * 64 + tt) * 512 + h * 32 + c4;
      float4 kx = *(const float4*)kp;
      float4 vx = *(const float4*)(kp + 256);
      kx.x *= sc; kx.y *= sc; kx.z *= sc; kx.w *= sc;
      vx.x *= sc; vx.y *= sc; vx.z *= sc; vx.w *= sc;
      *(float4*)&ks[row][c4] = kx;
      *(float4*)&vs[row][c4] = vx;
    }
  }
  int t = tid >> 2, sub = tid & 3;
  float4 qreg[8];
  const float* qrow = q + ((size_t)b * T_LEN + (size_t)ib * 64 + t) * DIMC + h * 32;
#pragma unroll
  for (int c = 0; c < 8; c++) qreg[c] = *(const float4*)(qrow + c * 4);
  __syncthreads();
  // scores for u = j*4 + sub
  float scv[32];
#pragma unroll 4
  for (int j = 0; j < 32; j++) {
    int u = (j << 2) + sub;
    float s = 0.f;
#pragma unroll
    for (int c = 0; c < 8; c++) {
      float4 k4 = *(float4*)&ks[u][c * 4];
      s += qreg[c].x * k4.x + qreg[c].y * k4.y + qreg[c].z * k4.z + qreg[c].w * k4.w;
    }
    scv[j] = s * 0.17677669529663687f;
  }
  float m = -1e30f;
#pragma unroll
  for (int j = 0; j < 32; j++) m = fmaxf(m, scv[j]);
  m = fmaxf(m, __shfl_xor(m, 1));
  m = fmaxf(m, __shfl_xor(m, 2));
  float sum = 0.f;
#pragma unroll
  for (int j = 0; j < 32; j++) {
    scv[j] = expf(scv[j] - m);
    sum += scv[j];
  }
  sum += __shfl_xor(sum, 1);
  sum += __shfl_xor(sum, 2);
  float inv = 1.0f / sum;
#pragma unroll
  for (int j = 0; j < 32; j++) scv[j] *= inv;
  float outv[32];
#pragma unroll
  for (int i = 0; i < 32; i++) outv[i] = 0.f;
#pragma unroll 4
  for (int j = 0; j < 32; j++) {
    int u = (j << 2) + sub;
    float pv = scv[j];
#pragma unroll
    for (int c = 0; c < 8; c++) {
      float4 v4 = *(float4*)&vs[u][c * 4];
      outv[c * 4 + 0] += pv * v4.x;
      outv[c * 4 + 1] += pv * v4.y;
      outv[c * 4 + 2] += pv * v4.z;
      outv[c * 4 + 3] += pv * v4.w;
    }
  }
#pragma unroll
  for (int i = 0; i < 32; i++) {
    outv[i] += __shfl_xor(outv[i], 1);
    outv[i] += __shfl_xor(outv[i], 2);
  }
  ushort* orow = o + ((size_t)b * T_LEN + (size_t)ib * 64 + t) * DIMC + h * 32 + sub * 8;
  ushort4 w0, w1;
  w0.x = f2bf(outv[sub * 8 + 0]); w0.y = f2bf(outv[sub * 8 + 1]);
  w0.z = f2bf(outv[sub * 8 + 2]); w0.w = f2bf(outv[sub * 8 + 3]);
  w1.x = f2bf(outv[sub * 8 + 4]); w1.y = f2bf(outv[sub * 8 + 5]);
  w1.z = f2bf(outv[sub * 8 + 6]); w1.w = f2bf(outv[sub * 8 + 7]);
  *(ushort4*)(orow) = w0;
  *(ushort4*)(orow + 4) = w1;
}

// ---------------------------------------------------------------------------
// out[b,d,t] = yln[b,t,d]
// ---------------------------------------------------------------------------
__global__ __launch_bounds__(256)
void transpose_out_k(const float* __restrict__ yln, float* __restrict__ out) {
  __shared__ float tile[32][33];
  int b  = blockIdx.z;
  int t0 = blockIdx.x * 32;
  int d0 = blockIdx.y * 32;
  int tx = threadIdx.x;
  int ty = threadIdx.y;
#pragma unroll
  for (int k = 0; k < 4; k++) {
    int t = t0 + ty + k * 8;
    tile[ty + k * 8][tx] = yln[((size_t)b * T_LEN + t) * DIMC + d0 + tx];
  }
  __syncthreads();
#pragma unroll
  for (int k = 0; k < 4; k++) {
    int d = d0 + ty + k * 8;
    out[((size_t)b * DIMC + d) * T_LEN + t0 + tx] = tile[tx][ty + k * 8];
  }
}

// ---------------------------------------------------------------------------
extern "C" void kernel_launch(void* const* d_in, const int* in_sizes, int n_in,
                              void* d_out, int out_size, void* d_ws, size_t ws_size,
                              hipStream_t stream) {
  const float* x     = (const float*)d_in[0];
  const float* pe0   = (const float*)d_in[1];
  const float* pe1   = (const float*)d_in[2];
  const float* ln1_g = (const float*)d_in[3];
  const float* ln1_b = (const float*)d_in[4];
  const float* Wq    = (const float*)d_in[5];
  const float* Wkv   = (const float*)d_in[6];
  const float* Wo    = (const float*)d_in[7];
  const float* bo    = (const float*)d_in[8];
  const float* ln2_g = (const float*)d_in[9];
  const float* ln2_b = (const float*)d_in[10];
  const float* W1    = (const float*)d_in[11];
  const float* b1    = (const float*)d_in[12];
  const float* W2    = (const float*)d_in[13];
  const float* b2    = (const float*)d_in[14];
  const float* gf    = (const float*)d_in[15];
  const float* bfp   = (const float*)d_in[16];
  float* out = (float*)d_out;

  const int M = MROWS;
  // workspace layout
  float*  y    = (float*)d_ws;                   // M*256 fp32
  float*  qb   = y + (size_t)M * 256;            // M*256 fp32
  float*  kvb  = qb + (size_t)M * 256;           // M*512 fp32 (aliased bf16 M*1024 for FF)
  ushort* hbf  = (ushort*)(kvb + (size_t)M * 512); // M*256 bf16
  ushort* wbf  = hbf + (size_t)M * 256;          // 6 * 786432 bf16 weights (transposed)
  float*  sqb  = (float*)(wbf + (size_t)6 * 786432);
  float*  skb  = sqb + 32 * 128 * 32;
  float*  rwb  = skb + 32 * 128 * 32;
  int*    rib  = (int*)(rwb + 4096);
  ushort* ffbf = (ushort*)kvb;

  dim3 tb(32, 8);
  // weight conversion (bf16, transposed): per-layer offsets in 786432-ushort blocks
  wt_bf16_k<<<dim3(8, 8, 6),  tb, 0, stream>>>(Wq,  wbf + 0,      256, 256,  786432);
  wt_bf16_k<<<dim3(16, 8, 6), tb, 0, stream>>>(Wkv, wbf + 65536,  256, 512,  786432);
  wt_bf16_k<<<dim3(8, 8, 6),  tb, 0, stream>>>(Wo,  wbf + 196608, 256, 256,  786432);
  wt_bf16_k<<<dim3(32, 8, 6), tb, 0, stream>>>(W1,  wbf + 262144, 256, 1024, 786432);
  wt_bf16_k<<<dim3(8, 32, 6), tb, 0, stream>>>(W2,  wbf + 524288, 1024, 256, 786432);

  add_pos_k<<<dim3(T_LEN / 32, DIMC / 32, 4), tb, 0, stream>>>(x, pe0, pe1, y);

  for (int l = 0; l < 6; l++) {
    const ushort* wl   = wbf + (size_t)l * 786432;
    const ushort* wqT  = wl;
    const ushort* wkvT = wl + 65536;
    const ushort* woT  = wl + 196608;
    const ushort* w1T  = wl + 262144;
    const ushort* w2T  = wl + 524288;

    layernorm_k<1><<<M / 4, 256, 0, stream>>>(y, ln1_g + l * 256, ln1_b + l * 256, hbf);
    gemm_bf16<0><<<dim3(2, M / 128), 256, 0, stream>>>(hbf, wqT, nullptr, qb, nullptr, 256, 256);
    gemm_bf16<0><<<dim3(4, M / 128), 256, 0, stream>>>(hbf, wkvT, nullptr, kvb, nullptr, 512, 256);
    summary_k<<<BHEAD * NBUCK, 64, 0, stream>>>(qb, kvb, sqb, skb);
    route_k<<<BHEAD * NBUCK, 64, 0, stream>>>(sqb, skb, rib, rwb);
    attn_k<<<BHEAD * NBUCK, 256, 0, stream>>>(qb, kvb, rib, rwb, hbf);
    gemm_bf16<2><<<dim3(2, M / 128), 256, 0, stream>>>(hbf, woT, bo + l * 256, y, nullptr, 256, 256);
    layernorm_k<1><<<M / 4, 256, 0, stream>>>(y, ln2_g + l * 256, ln2_b + l * 256, hbf);
    gemm_bf16<1><<<dim3(8, M / 128), 256, 0, stream>>>(hbf, w1T, b1 + l * 1024, nullptr, ffbf, 1024, 256);
    gemm_bf16<2><<<dim3(2, M / 128), 256, 0, stream>>>(ffbf, w2T, b2 + l * 256, y, nullptr, 256, 1024);
  }

  layernorm_k<0><<<M / 4, 256, 0, stream>>>(y, gf, bfp, qb);
  transpose_out_k<<<dim3(T_LEN / 32, DIMC / 32, 4), tb, 0, stream>>>(qb, out);

  (void)in_sizes; (void)n_in; (void)out_size; (void)ws_size;
}

// Round 3
// 1722.312 us; speedup vs baseline: 3.7962x; 1.2180x over previous
//
#include <hip/hip_runtime.h>
#include <cstdint>
#include <cstddef>

#define T_LEN 8192
#define DIMC  256
#define NBUCK 128
#define BHEAD 32
#define MROWS 32768

typedef __attribute__((ext_vector_type(8))) short bf16x8;
typedef __attribute__((ext_vector_type(4))) float f32x4;

__device__ __forceinline__ ushort f2bf(float x) {
  union { float f; unsigned u; } v; v.f = x;
  unsigned r = v.u + 0x7fffu + ((v.u >> 16) & 1u);
  return (ushort)(r >> 16);
}
__device__ __forceinline__ float bf2f(ushort u) {
  union { unsigned u; float f; } v; v.u = ((unsigned)u) << 16; return v.f;
}

__device__ __forceinline__ void gld16(const void* g, void* l) {
  __builtin_amdgcn_global_load_lds((const __attribute__((address_space(1))) void*)g,
                                   (__attribute__((address_space(3))) void*)l, 16, 0, 0);
}

// ---------------------------------------------------------------------------
// y[b,t,d] = x[b,d,t] + pe0[t/64,d] + pe1[t%64,d]
// ---------------------------------------------------------------------------
__global__ __launch_bounds__(256)
void add_pos_k(const float* __restrict__ x, const float* __restrict__ pe0,
               const float* __restrict__ pe1, float* __restrict__ y) {
  __shared__ float tile[32][33];
  int b  = blockIdx.z;
  int t0 = blockIdx.x * 32;
  int d0 = blockIdx.y * 32;
  int tj = threadIdx.x;
  int di = threadIdx.y;
#pragma unroll
  for (int k = 0; k < 4; k++) {
    int d = d0 + di + k * 8;
    tile[di + k * 8][tj] = x[((size_t)b * DIMC + d) * T_LEN + t0 + tj];
  }
  __syncthreads();
#pragma unroll
  for (int k = 0; k < 4; k++) {
    int t = t0 + di + k * 8;
    int d = d0 + tj;
    y[((size_t)b * T_LEN + t) * DIMC + d] =
        tile[tj][di + k * 8] + pe0[(size_t)(t >> 6) * DIMC + d] + pe1[(size_t)(t & 63) * DIMC + d];
  }
}

// ---------------------------------------------------------------------------
// LayerNorm over last dim (256). One wave per row, 4 rows per block.
// BF=1: write bf16, BF=0: write fp32.
// ---------------------------------------------------------------------------
template <int BF>
__global__ __launch_bounds__(256)
void layernorm_k(const float* __restrict__ x, const float* __restrict__ g,
                 const float* __restrict__ b, void* __restrict__ o) {
  int row  = blockIdx.x * 4 + (threadIdx.x >> 6);
  int lane = threadIdx.x & 63;
  const float4* xr = (const float4*)(x + (size_t)row * DIMC);
  float4 v = xr[lane];
  float s  = v.x + v.y + v.z + v.w;
  float s2 = v.x * v.x + v.y * v.y + v.z * v.z + v.w * v.w;
#pragma unroll
  for (int off = 32; off; off >>= 1) {
    s  += __shfl_xor(s, off);
    s2 += __shfl_xor(s2, off);
  }
  float mean = s * (1.0f / 256.0f);
  float var  = s2 * (1.0f / 256.0f) - mean * mean;
  float r    = rsqrtf(var + 1e-5f);
  float4 gv = ((const float4*)g)[lane];
  float4 bv = ((const float4*)b)[lane];
  float4 ov;
  ov.x = (v.x - mean) * r * gv.x + bv.x;
  ov.y = (v.y - mean) * r * gv.y + bv.y;
  ov.z = (v.z - mean) * r * gv.z + bv.z;
  ov.w = (v.w - mean) * r * gv.w + bv.w;
  if (BF) {
    ushort4 o4;
    o4.x = f2bf(ov.x); o4.y = f2bf(ov.y); o4.z = f2bf(ov.z); o4.w = f2bf(ov.w);
    ((ushort4*)((ushort*)o + (size_t)row * DIMC))[lane] = o4;
  } else {
    ((float4*)((float*)o + (size_t)row * DIMC))[lane] = ov;
  }
}

// ---------------------------------------------------------------------------
// weight convert: Wt[l][n][k] = bf16(W[l][k][n])
// ---------------------------------------------------------------------------
__global__ __launch_bounds__(256)
void wt_bf16_k(const float* __restrict__ W, ushort* __restrict__ Wt,
               int K, int N, size_t outStride) {
  __shared__ float t[32][33];
  int l = blockIdx.z;
  const float* Wl = W + (size_t)l * K * N;
  ushort* Wtl = Wt + (size_t)l * outStride;
  int n0 = blockIdx.x * 32, k0 = blockIdx.y * 32;
  int tx = threadIdx.x, ty = threadIdx.y;
#pragma unroll
  for (int p = 0; p < 4; p++)
    t[ty + p * 8][tx] = Wl[(size_t)(k0 + ty + p * 8) * N + n0 + tx];
  __syncthreads();
#pragma unroll
  for (int p = 0; p < 4; p++)
    Wtl[(size_t)(n0 + ty + p * 8) * K + k0 + tx] = f2bf(t[tx][ty + p * 8]);
}

// ---------------------------------------------------------------------------
// bf16 MFMA GEMM: epi(A(MxK,lda) @ Bt(NxK,ldb)^T + bias)
// EPI 0: store bf16.  EPI 1: gelu -> bf16.  EPI 2: C(fp32) += . + bias.
// 128x128 tile, BK=32, 256 threads (2x2 waves), 4x4 MFMA 16x16x32 per wave.
// ---------------------------------------------------------------------------
template <int EPI>
__global__ __launch_bounds__(256)
void gemm_bf16(const ushort* __restrict__ A, const ushort* __restrict__ Bt,
               const float* __restrict__ bias, float* __restrict__ C,
               ushort* __restrict__ Cbf, int N, int K, int lda, int ldb) {
  __shared__ ushort As[128 * 32];
  __shared__ ushort Bs[128 * 32];
  int tid = threadIdx.x;
  int w = tid >> 6, lane = tid & 63;
  int bm = blockIdx.y << 7, bn = blockIdx.x << 7;
  int wm = (w >> 1) << 6, wn = (w & 1) << 6;
  int l15 = lane & 15, quad = lane >> 4;

  int off0 = (w << 11) + (lane << 4);
  int off1 = off0 + 1024;
  int r0 = off0 >> 6, c0 = (off0 & 63) >> 1;
  int r1 = off1 >> 6, c1 = (off1 & 63) >> 1;
  const ushort* ga0 = A + (size_t)(bm + r0) * lda + c0;
  const ushort* ga1 = A + (size_t)(bm + r1) * lda + c1;
  const ushort* gb0 = Bt + (size_t)(bn + r0) * ldb + c0;
  const ushort* gb1 = Bt + (size_t)(bn + r1) * ldb + c1;
  ushort* lA0 = As + (w << 10);
  ushort* lA1 = lA0 + 512;
  ushort* lB0 = Bs + (w << 10);
  ushort* lB1 = lB0 + 512;

  f32x4 acc[4][4];
#pragma unroll
  for (int i = 0; i < 4; i++)
#pragma unroll
    for (int j = 0; j < 4; j++) {
      f32x4 z = {0.f, 0.f, 0.f, 0.f};
      acc[i][j] = z;
    }

  for (int k0 = 0; k0 < K; k0 += 32) {
    gld16(ga0 + k0, lA0);
    gld16(ga1 + k0, lA1);
    gld16(gb0 + k0, lB0);
    gld16(gb1 + k0, lB1);
    __syncthreads();
    bf16x8 aF[4], bF[4];
#pragma unroll
    for (int i = 0; i < 4; i++)
      aF[i] = *(const bf16x8*)(As + ((wm + (i << 4) + l15) << 5) + (quad << 3));
#pragma unroll
    for (int j = 0; j < 4; j++)
      bF[j] = *(const bf16x8*)(Bs + ((wn + (j << 4) + l15) << 5) + (quad << 3));
#pragma unroll
    for (int i = 0; i < 4; i++)
#pragma unroll
      for (int j = 0; j < 4; j++)
        acc[i][j] = __builtin_amdgcn_mfma_f32_16x16x32_bf16(aF[i], bF[j], acc[i][j], 0, 0, 0);
    __syncthreads();
  }

#pragma unroll
  for (int j = 0; j < 4; j++) {
    int col = bn + wn + (j << 4) + l15;
    float bv = bias ? bias[col] : 0.f;
#pragma unroll
    for (int i = 0; i < 4; i++) {
      int rowb = bm + wm + (i << 4) + (quad << 2);
#pragma unroll
      for (int r = 0; r < 4; r++) {
        float v = acc[i][j][r];
        size_t idx = (size_t)(rowb + r) * N + col;
        if (EPI == 0) {
          Cbf[idx] = f2bf(v);
        } else if (EPI == 1) {
          v += bv;
          v = 0.5f * v * (1.0f + erff(v * 0.70710678118654752f));
          Cbf[idx] = f2bf(v);
        } else {
          C[idx] = C[idx] + v + bv;
        }
      }
    }
  }
}

// ---------------------------------------------------------------------------
// bucket summaries from bf16 q/kv
// ---------------------------------------------------------------------------
__global__ __launch_bounds__(64)
void summary_k(const ushort* __restrict__ q, const ushort* __restrict__ kv,
               float* __restrict__ sq, float* __restrict__ sk) {
  int blk = blockIdx.x;
  int bh = blk >> 7, ib = blk & 127;
  int b = bh >> 3, h = bh & 7;
  int lane = threadIdx.x;
  int d = lane & 31;
  bool isK = lane >= 32;
  const ushort* src = isK ? kv : q;
  size_t rs = isK ? 512 : 256;
  size_t base = ((size_t)b * T_LEN + (size_t)ib * 64) * rs + h * 32 + d;
  float s = 0.f;
#pragma unroll 8
  for (int t = 0; t < 64; t++) s += bf2f(src[base + (size_t)t * rs]);
  s *= (1.0f / 64.0f);
  float* dst = isK ? sk : sq;
  dst[((size_t)bh * NBUCK + ib) * 32 + d] = s;
}

// ---------------------------------------------------------------------------
// routing (fp32 summaries)
// ---------------------------------------------------------------------------
__global__ __launch_bounds__(64)
void route_k(const float* __restrict__ sq, const float* __restrict__ sk,
             int* __restrict__ ridx, float* __restrict__ rw) {
  int blk = blockIdx.x;
  int bh = blk >> 7, ib = blk & 127;
  int lane = threadIdx.x;
  const float* qrow = sq + ((size_t)bh * NBUCK + ib) * 32;
  const float* k0 = sk + ((size_t)bh * NBUCK + lane) * 32;
  const float* k1 = k0 + 64 * 32;
  float s0 = 0.f, s1 = 0.f;
#pragma unroll
  for (int d = 0; d < 32; d++) {
    float qd = qrow[d];
    s0 += qd * k0[d];
    s1 += qd * k1[d];
  }
  const float sc = 0.17677669529663687f * (4.0f / 3.0f);
  float L0 = s0 * sc, L1 = s1 * sc;
  float m = fmaxf(L0, L1);
#pragma unroll
  for (int off = 32; off; off >>= 1) m = fmaxf(m, __shfl_xor(m, off));
  float Z = expf(L0 - m) + expf(L1 - m);
#pragma unroll
  for (int off = 32; off; off >>= 1) Z += __shfl_xor(Z, off);
  float mv = (L1 > L0) ? L1 : L0;
  int mj = (L1 > L0) ? lane + 64 : lane;
#pragma unroll
  for (int off = 32; off; off >>= 1) {
    float ov = __shfl_xor(mv, off);
    int oj = __shfl_xor(mj, off);
    if (ov > mv || (ov == mv && oj < mj)) { mv = ov; mj = oj; }
  }
  if (lane == 0) {
    ridx[blk] = mj;
    rw[blk] = 1.0f / Z;
  }
}

// ---------------------------------------------------------------------------
// MFMA bucketed attention. grid BH*NB, 256 threads (4 waves).
// Wave w owns Q rows [w*16, w*16+16). Routing weight w folded into fp32
// score cols (<64) pre-softmax and into P cols (<64) pre-PV.
// ---------------------------------------------------------------------------
__global__ __launch_bounds__(256)
void attn_mfma_k(const ushort* __restrict__ q, const ushort* __restrict__ kv,
                 const int* __restrict__ ridx, const float* __restrict__ rw,
                 ushort* __restrict__ o) {
  __shared__ ushort Qs[64][40];
  __shared__ ushort Ks[128][40];
  __shared__ ushort Vt[32][136];
  __shared__ ushort Ps[4][16][136];
  int blk = blockIdx.x;
  int bh = blk >> 7, ib = blk & 127;
  int b = bh >> 3, h = bh & 7;
  int tid = threadIdx.x;
  int jr = ridx[blk];
  float w = rw[blk];
  // stage Q
  {
    int r = tid >> 2, c = (tid & 3) << 3;
    const ushort* src = q + ((size_t)b * T_LEN + (size_t)ib * 64 + r) * 256 + h * 32 + c;
    *(bf16x8*)&Qs[r][c] = *(const bf16x8*)src;
  }
  // stage K (rows 0-63 routed bucket jr, 64-127 own bucket ib)
#pragma unroll
  for (int p = 0; p < 2; p++) {
    int idx = tid + (p << 8);
    int r = idx >> 2, c = (idx & 3) << 3;
    int srcb = (r < 64) ? jr : ib;
    int tt = r & 63;
    const ushort* src = kv + ((size_t)b * T_LEN + (size_t)srcb * 64 + tt) * 512 + h * 32 + c;
    *(bf16x8*)&Ks[r][c] = *(const bf16x8*)src;
  }
  // stage V^T
  {
    int tok = tid >> 1, d0 = (tid & 1) << 4;
    int srcb = (tok < 64) ? jr : ib;
    int tt = tok & 63;
    const ushort* src = kv + ((size_t)b * T_LEN + (size_t)srcb * 64 + tt) * 512 + 256 + h * 32 + d0;
    bf16x8 v0 = *(const bf16x8*)src;
    bf16x8 v1 = *(const bf16x8*)(src + 8);
#pragma unroll
    for (int j = 0; j < 8; j++) {
      Vt[d0 + j][tok] = (ushort)v0[j];
      Vt[d0 + 8 + j][tok] = (ushort)v1[j];
    }
  }
  __syncthreads();
  int wid = tid >> 6, lane = tid & 63, l15 = lane & 15, quad = lane >> 4;
  // S = Q K^T  (wave tile 16x128)
  bf16x8 aQ = *(const bf16x8*)&Qs[(wid << 4) + l15][quad << 3];
  f32x4 sf[8];
#pragma unroll
  for (int jn = 0; jn < 8; jn++) {
    bf16x8 bK = *(const bf16x8*)&Ks[(jn << 4) + l15][quad << 3];
    f32x4 z = {0.f, 0.f, 0.f, 0.f};
    sf[jn] = __builtin_amdgcn_mfma_f32_16x16x32_bf16(aQ, bK, z, 0, 0, 0);
  }
  const float sc = 0.17677669529663687f;
#pragma unroll
  for (int jn = 0; jn < 8; jn++) {
    float mult = (jn < 4) ? w * sc : sc;
#pragma unroll
    for (int r = 0; r < 4; r++) sf[jn][r] *= mult;
  }
  // softmax (rows quad*4+r, cols across jn & l15)
  float mx[4], sm[4], inv[4];
#pragma unroll
  for (int r = 0; r < 4; r++) {
    float m = sf[0][r];
#pragma unroll
    for (int jn = 1; jn < 8; jn++) m = fmaxf(m, sf[jn][r]);
    mx[r] = m;
  }
#pragma unroll
  for (int off = 1; off < 16; off <<= 1)
#pragma unroll
    for (int r = 0; r < 4; r++) mx[r] = fmaxf(mx[r], __shfl_xor(mx[r], off));
#pragma unroll
  for (int r = 0; r < 4; r++) sm[r] = 0.f;
#pragma unroll
  for (int jn = 0; jn < 8; jn++)
#pragma unroll
    for (int r = 0; r < 4; r++) {
      sf[jn][r] = expf(sf[jn][r] - mx[r]);
      sm[r] += sf[jn][r];
    }
#pragma unroll
  for (int off = 1; off < 16; off <<= 1)
#pragma unroll
    for (int r = 0; r < 4; r++) sm[r] += __shfl_xor(sm[r], off);
#pragma unroll
  for (int r = 0; r < 4; r++) inv[r] = 1.0f / sm[r];
  // P -> bf16 in per-wave LDS (C-layout -> A-layout transform)
#pragma unroll
  for (int jn = 0; jn < 8; jn++) {
    float ws2 = (jn < 4) ? w : 1.f;
#pragma unroll
    for (int r = 0; r < 4; r++)
      Ps[wid][(quad << 2) + r][(jn << 4) + l15] = f2bf(sf[jn][r] * inv[r] * ws2);
  }
  // O = P V  (16x32, K=128)
  f32x4 of[2];
#pragma unroll
  for (int nd = 0; nd < 2; nd++) { f32x4 z = {0.f, 0.f, 0.f, 0.f}; of[nd] = z; }
#pragma unroll
  for (int kk = 0; kk < 4; kk++) {
    bf16x8 aP = *(const bf16x8*)&Ps[wid][l15][(kk << 5) + (quad << 3)];
#pragma unroll
    for (int nd = 0; nd < 2; nd++) {
      bf16x8 bV = *(const bf16x8*)&Vt[(nd << 4) + l15][(kk << 5) + (quad << 3)];
      of[nd] = __builtin_amdgcn_mfma_f32_16x16x32_bf16(aP, bV, of[nd], 0, 0, 0);
    }
  }
  ushort* obase = o + ((size_t)b * T_LEN + (size_t)ib * 64 + (wid << 4) + (quad << 2)) * 256 + h * 32 + l15;
#pragma unroll
  for (int nd = 0; nd < 2; nd++)
#pragma unroll
    for (int r = 0; r < 4; r++)
      obase[(size_t)r * 256 + (nd << 4)] = f2bf(of[nd][r]);
}

// ---------------------------------------------------------------------------
// out[b,d,t] = yln[b,t,d]
// ---------------------------------------------------------------------------
__global__ __launch_bounds__(256)
void transpose_out_k(const float* __restrict__ yln, float* __restrict__ out) {
  __shared__ float tile[32][33];
  int b  = blockIdx.z;
  int t0 = blockIdx.x * 32;
  int d0 = blockIdx.y * 32;
  int tx = threadIdx.x;
  int ty = threadIdx.y;
#pragma unroll
  for (int k = 0; k < 4; k++) {
    int t = t0 + ty + k * 8;
    tile[ty + k * 8][tx] = yln[((size_t)b * T_LEN + t) * DIMC + d0 + tx];
  }
  __syncthreads();
#pragma unroll
  for (int k = 0; k < 4; k++) {
    int d = d0 + ty + k * 8;
    out[((size_t)b * DIMC + d) * T_LEN + t0 + tx] = tile[tx][ty + k * 8];
  }
}

// ---------------------------------------------------------------------------
extern "C" void kernel_launch(void* const* d_in, const int* in_sizes, int n_in,
                              void* d_out, int out_size, void* d_ws, size_t ws_size,
                              hipStream_t stream) {
  const float* x     = (const float*)d_in[0];
  const float* pe0   = (const float*)d_in[1];
  const float* pe1   = (const float*)d_in[2];
  const float* ln1_g = (const float*)d_in[3];
  const float* ln1_b = (const float*)d_in[4];
  const float* Wq    = (const float*)d_in[5];
  const float* Wkv   = (const float*)d_in[6];
  const float* Wo    = (const float*)d_in[7];
  const float* bo    = (const float*)d_in[8];
  const float* ln2_g = (const float*)d_in[9];
  const float* ln2_b = (const float*)d_in[10];
  const float* W1    = (const float*)d_in[11];
  const float* b1    = (const float*)d_in[12];
  const float* W2    = (const float*)d_in[13];
  const float* b2    = (const float*)d_in[14];
  const float* gf    = (const float*)d_in[15];
  const float* bfp   = (const float*)d_in[16];
  float* out = (float*)d_out;

  const int M = MROWS;
  float*  y    = (float*)d_ws;                       // M*256 f32
  ushort* qbf  = (ushort*)(y + (size_t)M * 256);     // M*256 bf16
  ushort* kvbf = qbf + (size_t)M * 256;              // M*512 bf16 (ff intermediate aliases)
  ushort* hbf  = kvbf + (size_t)M * 512;             // M*256 bf16
  ushort* wbf  = hbf + (size_t)M * 256;              // 6*786432 bf16 (transposed weights)
  float*  yfin = (float*)(wbf + (size_t)6 * 786432); // M*256 f32
  float*  sqb  = yfin + (size_t)M * 256;
  float*  skb  = sqb + 32 * 128 * 32;
  float*  rwb  = skb + 32 * 128 * 32;
  int*    rib  = (int*)(rwb + 4096);
  ushort* ffbf = kvbf;   // ff half intermediate (kv dead after attention)

  dim3 tb(32, 8);
  wt_bf16_k<<<dim3(8, 8, 6),  tb, 0, stream>>>(Wq,  wbf + 0,      256, 256,  786432);
  wt_bf16_k<<<dim3(16, 8, 6), tb, 0, stream>>>(Wkv, wbf + 65536,  256, 512,  786432);
  wt_bf16_k<<<dim3(8, 8, 6),  tb, 0, stream>>>(Wo,  wbf + 196608, 256, 256,  786432);
  wt_bf16_k<<<dim3(32, 8, 6), tb, 0, stream>>>(W1,  wbf + 262144, 256, 1024, 786432);
  wt_bf16_k<<<dim3(8, 32, 6), tb, 0, stream>>>(W2,  wbf + 524288, 1024, 256, 786432);

  add_pos_k<<<dim3(T_LEN / 32, DIMC / 32, 4), tb, 0, stream>>>(x, pe0, pe1, y);

  for (int l = 0; l < 6; l++) {
    const ushort* wl   = wbf + (size_t)l * 786432;
    const ushort* wqT  = wl;
    const ushort* wkvT = wl + 65536;
    const ushort* woT  = wl + 196608;
    const ushort* w1T  = wl + 262144;
    const ushort* w2T  = wl + 524288;

    layernorm_k<1><<<M / 4, 256, 0, stream>>>(y, ln1_g + l * 256, ln1_b + l * 256, hbf);
    gemm_bf16<0><<<dim3(2, M / 128), 256, 0, stream>>>(hbf, wqT, nullptr, nullptr, qbf, 256, 256, 256, 256);
    gemm_bf16<0><<<dim3(4, M / 128), 256, 0, stream>>>(hbf, wkvT, nullptr, nullptr, kvbf, 512, 256, 256, 256);
    summary_k<<<BHEAD * NBUCK, 64, 0, stream>>>(qbf, kvbf, sqb, skb);
    route_k<<<BHEAD * NBUCK, 64, 0, stream>>>(sqb, skb, rib, rwb);
    attn_mfma_k<<<BHEAD * NBUCK, 256, 0, stream>>>(qbf, kvbf, rib, rwb, hbf);
    gemm_bf16<2><<<dim3(2, M / 128), 256, 0, stream>>>(hbf, woT, bo + l * 256, y, nullptr, 256, 256, 256, 256);
    layernorm_k<1><<<M / 4, 256, 0, stream>>>(y, ln2_g + l * 256, ln2_b + l * 256, hbf);
    // FF in two 512-wide halves (intermediate aliases kvbf)
    gemm_bf16<1><<<dim3(4, M / 128), 256, 0, stream>>>(hbf, w1T, b1 + l * 1024, nullptr, ffbf, 512, 256, 256, 256);
    gemm_bf16<2><<<dim3(2, M / 128), 256, 0, stream>>>(ffbf, w2T, b2 + l * 256, y, nullptr, 256, 512, 512, 1024);
    gemm_bf16<1><<<dim3(4, M / 128), 256, 0, stream>>>(hbf, w1T + (size_t)512 * 256, b1 + l * 1024 + 512, nullptr, ffbf, 512, 256, 256, 256);
    gemm_bf16<2><<<dim3(2, M / 128), 256, 0, stream>>>(ffbf, w2T + 512, nullptr, y, nullptr, 256, 512, 512, 1024);
  }

  layernorm_k<0><<<M / 4, 256, 0, stream>>>(y, gf, bfp, yfin);
  transpose_out_k<<<dim3(T_LEN / 32, DIMC / 32, 4), tb, 0, stream>>>(yfin, out);

  (void)in_sizes; (void)n_in; (void)out_size; (void)ws_size;
}

// Round 4
// 1566.041 us; speedup vs baseline: 4.1751x; 1.0998x over previous
//
#include <hip/hip_runtime.h>
#include <cstdint>
#include <cstddef>

#define T_LEN 8192
#define DIMC  256
#define NBUCK 128
#define BHEAD 32
#define MROWS 32768

typedef __attribute__((ext_vector_type(8))) short bf16x8;
typedef __attribute__((ext_vector_type(4))) float f32x4;

__device__ __forceinline__ ushort f2bf(float x) {
  union { float f; unsigned u; } v; v.f = x;
  unsigned r = v.u + 0x7fffu + ((v.u >> 16) & 1u);
  return (ushort)(r >> 16);
}
__device__ __forceinline__ float bf2f(ushort u) {
  union { unsigned u; float f; } v; v.u = ((unsigned)u) << 16; return v.f;
}

__device__ __forceinline__ void gld16(const void* g, void* l) {
  __builtin_amdgcn_global_load_lds((const __attribute__((address_space(1))) void*)g,
                                   (__attribute__((address_space(3))) void*)l, 16, 0, 0);
}

// ---------------------------------------------------------------------------
// y[b,t,d] = x[b,d,t] + pe0[t/64,d] + pe1[t%64,d]
// ---------------------------------------------------------------------------
__global__ __launch_bounds__(256)
void add_pos_k(const float* __restrict__ x, const float* __restrict__ pe0,
               const float* __restrict__ pe1, float* __restrict__ y) {
  __shared__ float tile[32][33];
  int b  = blockIdx.z;
  int t0 = blockIdx.x * 32;
  int d0 = blockIdx.y * 32;
  int tj = threadIdx.x;
  int di = threadIdx.y;
#pragma unroll
  for (int k = 0; k < 4; k++) {
    int d = d0 + di + k * 8;
    tile[di + k * 8][tj] = x[((size_t)b * DIMC + d) * T_LEN + t0 + tj];
  }
  __syncthreads();
#pragma unroll
  for (int k = 0; k < 4; k++) {
    int t = t0 + di + k * 8;
    int d = d0 + tj;
    y[((size_t)b * T_LEN + t) * DIMC + d] =
        tile[tj][di + k * 8] + pe0[(size_t)(t >> 6) * DIMC + d] + pe1[(size_t)(t & 63) * DIMC + d];
  }
}

// ---------------------------------------------------------------------------
// Standalone LayerNorm (used once, for layer 0's LN1). Writes bf16.
// ---------------------------------------------------------------------------
__global__ __launch_bounds__(256)
void layernorm_k(const float* __restrict__ x, const float* __restrict__ g,
                 const float* __restrict__ b, ushort* __restrict__ o) {
  int row  = blockIdx.x * 4 + (threadIdx.x >> 6);
  int lane = threadIdx.x & 63;
  const float4* xr = (const float4*)(x + (size_t)row * DIMC);
  float4 v = xr[lane];
  float s  = v.x + v.y + v.z + v.w;
  float s2 = v.x * v.x + v.y * v.y + v.z * v.z + v.w * v.w;
#pragma unroll
  for (int off = 32; off; off >>= 1) {
    s  += __shfl_xor(s, off);
    s2 += __shfl_xor(s2, off);
  }
  float mean = s * (1.0f / 256.0f);
  float var  = s2 * (1.0f / 256.0f) - mean * mean;
  float r    = rsqrtf(var + 1e-5f);
  float4 gv = ((const float4*)g)[lane];
  float4 bv = ((const float4*)b)[lane];
  ushort4 o4;
  o4.x = f2bf((v.x - mean) * r * gv.x + bv.x);
  o4.y = f2bf((v.y - mean) * r * gv.y + bv.y);
  o4.z = f2bf((v.z - mean) * r * gv.z + bv.z);
  o4.w = f2bf((v.w - mean) * r * gv.w + bv.w);
  ((ushort4*)(o + (size_t)row * DIMC))[lane] = o4;
}

// ---------------------------------------------------------------------------
// weight convert: Wt[l][n][k] = bf16(W[l][k][n])
// ---------------------------------------------------------------------------
__global__ __launch_bounds__(256)
void wt_bf16_k(const float* __restrict__ W, ushort* __restrict__ Wt,
               int K, int N, size_t outStride) {
  __shared__ float t[32][33];
  int l = blockIdx.z;
  const float* Wl = W + (size_t)l * K * N;
  ushort* Wtl = Wt + (size_t)l * outStride;
  int n0 = blockIdx.x * 32, k0 = blockIdx.y * 32;
  int tx = threadIdx.x, ty = threadIdx.y;
#pragma unroll
  for (int p = 0; p < 4; p++)
    t[ty + p * 8][tx] = Wl[(size_t)(k0 + ty + p * 8) * N + n0 + tx];
  __syncthreads();
#pragma unroll
  for (int p = 0; p < 4; p++)
    Wtl[(size_t)(n0 + ty + p * 8) * K + k0 + tx] = f2bf(t[tx][ty + p * 8]);
}

// ---------------------------------------------------------------------------
// bf16 MFMA GEMM: epi(A(MxK,lda) @ Bt(NxK,ldb)^T + bias) -> bf16
// EPI 0: store bf16.  EPI 1: gelu(.+bias) -> bf16.
// 128x128 tile, BK=32, 256 threads (2x2 waves), 4x4 MFMA 16x16x32 per wave.
// ---------------------------------------------------------------------------
template <int EPI>
__global__ __launch_bounds__(256)
void gemm_bf16(const ushort* __restrict__ A, const ushort* __restrict__ Bt,
               const float* __restrict__ bias, ushort* __restrict__ Cbf,
               int N, int K, int lda, int ldb) {
  __shared__ ushort As[128 * 32];
  __shared__ ushort Bs[128 * 32];
  int tid = threadIdx.x;
  int w = tid >> 6, lane = tid & 63;
  int bm = blockIdx.y << 7, bn = blockIdx.x << 7;
  int wm = (w >> 1) << 6, wn = (w & 1) << 6;
  int l15 = lane & 15, quad = lane >> 4;

  int off0 = (w << 11) + (lane << 4);
  int off1 = off0 + 1024;
  int r0 = off0 >> 6, c0 = (off0 & 63) >> 1;
  int r1 = off1 >> 6, c1 = (off1 & 63) >> 1;
  const ushort* ga0 = A + (size_t)(bm + r0) * lda + c0;
  const ushort* ga1 = A + (size_t)(bm + r1) * lda + c1;
  const ushort* gb0 = Bt + (size_t)(bn + r0) * ldb + c0;
  const ushort* gb1 = Bt + (size_t)(bn + r1) * ldb + c1;
  ushort* lA0 = As + (w << 10);
  ushort* lA1 = lA0 + 512;
  ushort* lB0 = Bs + (w << 10);
  ushort* lB1 = lB0 + 512;

  f32x4 acc[4][4];
#pragma unroll
  for (int i = 0; i < 4; i++)
#pragma unroll
    for (int j = 0; j < 4; j++) {
      f32x4 z = {0.f, 0.f, 0.f, 0.f};
      acc[i][j] = z;
    }

  for (int k0 = 0; k0 < K; k0 += 32) {
    gld16(ga0 + k0, lA0);
    gld16(ga1 + k0, lA1);
    gld16(gb0 + k0, lB0);
    gld16(gb1 + k0, lB1);
    __syncthreads();
    bf16x8 aF[4], bF[4];
#pragma unroll
    for (int i = 0; i < 4; i++)
      aF[i] = *(const bf16x8*)(As + ((wm + (i << 4) + l15) << 5) + (quad << 3));
#pragma unroll
    for (int j = 0; j < 4; j++)
      bF[j] = *(const bf16x8*)(Bs + ((wn + (j << 4) + l15) << 5) + (quad << 3));
#pragma unroll
    for (int i = 0; i < 4; i++)
#pragma unroll
      for (int j = 0; j < 4; j++)
        acc[i][j] = __builtin_amdgcn_mfma_f32_16x16x32_bf16(aF[i], bF[j], acc[i][j], 0, 0, 0);
    __syncthreads();
  }

#pragma unroll
  for (int j = 0; j < 4; j++) {
    int col = bn + wn + (j << 4) + l15;
    float bv = bias ? bias[col] : 0.f;
#pragma unroll
    for (int i = 0; i < 4; i++) {
      int rowb = bm + wm + (i << 4) + (quad << 2);
#pragma unroll
      for (int r = 0; r < 4; r++) {
        float v = acc[i][j][r];
        size_t idx = (size_t)(rowb + r) * N + col;
        if (EPI == 1) {
          v += bv;
          v = 0.5f * v * (1.0f + erff(v * 0.70710678118654752f));
        }
        Cbf[idx] = f2bf(v);
      }
    }
  }
}

// ---------------------------------------------------------------------------
// Fused GEMM + bias + residual + LayerNorm.
// Block: 64 rows x 256 cols (full row) -> LN computable in-block.
//   v = A@Bt^T + bias + y ; if !FINAL: y = v (new residual), obf = bf16(LN(v))
//   if FINAL: y = LN(v) (fp32, final output before transpose)
// 4 waves, each 64 rows x 64 cols. K multiple of 32.
// ---------------------------------------------------------------------------
template <int FINAL>
__global__ __launch_bounds__(256)
void gemm_fused_ln_k(const ushort* __restrict__ A, const ushort* __restrict__ Bt,
                     const float* __restrict__ bias, float* __restrict__ y,
                     const float* __restrict__ g, const float* __restrict__ b,
                     ushort* __restrict__ obf, int K, int lda) {
  __shared__ ushort As[64 * 32];    // 4KB
  __shared__ ushort Bs[256 * 32];   // 16KB
  __shared__ float red[4][64][2];
  __shared__ float stat[64][2];
  int tid = threadIdx.x;
  int wid = tid >> 6, lane = tid & 63;
  int l15 = lane & 15, quad = lane >> 4;
  int bm = blockIdx.x << 6;
  int wn = wid << 6;

  int ar = tid >> 2, ac = (tid & 3) << 3;
  const ushort* ga = A + (size_t)(bm + ar) * lda + ac;
  const ushort* gb0 = Bt + (size_t)(ar +   0) * K + ac;
  const ushort* gb1 = Bt + (size_t)(ar +  64) * K + ac;
  const ushort* gb2 = Bt + (size_t)(ar + 128) * K + ac;
  const ushort* gb3 = Bt + (size_t)(ar + 192) * K + ac;
  ushort* lA  = As + (wid << 9);
  ushort* lB0 = Bs + (wid << 9);
  ushort* lB1 = lB0 + 2048;
  ushort* lB2 = lB0 + 4096;
  ushort* lB3 = lB0 + 6144;

  f32x4 acc[4][4];
#pragma unroll
  for (int i = 0; i < 4; i++)
#pragma unroll
    for (int j = 0; j < 4; j++) {
      f32x4 z = {0.f, 0.f, 0.f, 0.f};
      acc[i][j] = z;
    }

  for (int k0 = 0; k0 < K; k0 += 32) {
    gld16(ga + k0, lA);
    gld16(gb0 + k0, lB0);
    gld16(gb1 + k0, lB1);
    gld16(gb2 + k0, lB2);
    gld16(gb3 + k0, lB3);
    __syncthreads();
    bf16x8 aF[4], bF[4];
#pragma unroll
    for (int i = 0; i < 4; i++)
      aF[i] = *(const bf16x8*)(As + (((i << 4) + l15) << 5) + (quad << 3));
#pragma unroll
    for (int j = 0; j < 4; j++)
      bF[j] = *(const bf16x8*)(Bs + ((wn + (j << 4) + l15) << 5) + (quad << 3));
#pragma unroll
    for (int i = 0; i < 4; i++)
#pragma unroll
      for (int j = 0; j < 4; j++)
        acc[i][j] = __builtin_amdgcn_mfma_f32_16x16x32_bf16(aF[i], bF[j], acc[i][j], 0, 0, 0);
    __syncthreads();
  }

  // phase 1: v = acc + bias + y_res; stash v; partial row sums
  float s1v[4][4] = {}, s2v[4][4] = {};
#pragma unroll
  for (int j = 0; j < 4; j++) {
    int col = wn + (j << 4) + l15;
    float bc = bias[col];
#pragma unroll
    for (int i = 0; i < 4; i++) {
#pragma unroll
      for (int r = 0; r < 4; r++) {
        int row = bm + (i << 4) + (quad << 2) + r;
        size_t idx = (size_t)row * 256 + col;
        float v = acc[i][j][r] + bc + y[idx];
        acc[i][j][r] = v;
        if (!FINAL) y[idx] = v;
        s1v[i][r] += v;
        s2v[i][r] += v * v;
      }
    }
  }
#pragma unroll
  for (int off = 1; off < 16; off <<= 1)
#pragma unroll
    for (int i = 0; i < 4; i++)
#pragma unroll
      for (int r = 0; r < 4; r++) {
        s1v[i][r] += __shfl_xor(s1v[i][r], off);
        s2v[i][r] += __shfl_xor(s2v[i][r], off);
      }
  if (l15 == 0) {
#pragma unroll
    for (int i = 0; i < 4; i++)
#pragma unroll
      for (int r = 0; r < 4; r++) {
        int rl = (i << 4) + (quad << 2) + r;
        red[wid][rl][0] = s1v[i][r];
        red[wid][rl][1] = s2v[i][r];
      }
  }
  __syncthreads();
  if (tid < 64) {
    float s  = red[0][tid][0] + red[1][tid][0] + red[2][tid][0] + red[3][tid][0];
    float s2 = red[0][tid][1] + red[1][tid][1] + red[2][tid][1] + red[3][tid][1];
    float mean = s * (1.0f / 256.0f);
    float var  = s2 * (1.0f / 256.0f) - mean * mean;
    stat[tid][0] = mean;
    stat[tid][1] = rsqrtf(var + 1e-5f);
  }
  __syncthreads();
#pragma unroll
  for (int j = 0; j < 4; j++) {
    int col = wn + (j << 4) + l15;
    float gc = g[col], bc2 = b[col];
#pragma unroll
    for (int i = 0; i < 4; i++) {
#pragma unroll
      for (int r = 0; r < 4; r++) {
        int rl = (i << 4) + (quad << 2) + r;
        float o = (acc[i][j][r] - stat[rl][0]) * stat[rl][1] * gc + bc2;
        size_t idx = (size_t)(bm + rl) * 256 + col;
        if (FINAL) y[idx] = o;
        else obf[idx] = f2bf(o);
      }
    }
  }
}

// ---------------------------------------------------------------------------
// bucket summaries from packed qkv (ld 768): q at +0, k at +256
// ---------------------------------------------------------------------------
__global__ __launch_bounds__(64)
void summary_k(const ushort* __restrict__ qkv,
               float* __restrict__ sq, float* __restrict__ sk) {
  int blk = blockIdx.x;
  int bh = blk >> 7, ib = blk & 127;
  int b = bh >> 3, h = bh & 7;
  int lane = threadIdx.x;
  int d = lane & 31;
  bool isK = lane >= 32;
  size_t base = ((size_t)b * T_LEN + (size_t)ib * 64) * 768 + (isK ? 256 : 0) + h * 32 + d;
  float s = 0.f;
#pragma unroll 8
  for (int t = 0; t < 64; t++) s += bf2f(qkv[base + (size_t)t * 768]);
  s *= (1.0f / 64.0f);
  float* dst = isK ? sk : sq;
  dst[((size_t)bh * NBUCK + ib) * 32 + d] = s;
}

// ---------------------------------------------------------------------------
// routing
// ---------------------------------------------------------------------------
__global__ __launch_bounds__(64)
void route_k(const float* __restrict__ sq, const float* __restrict__ sk,
             int* __restrict__ ridx, float* __restrict__ rw) {
  int blk = blockIdx.x;
  int bh = blk >> 7, ib = blk & 127;
  int lane = threadIdx.x;
  const float* qrow = sq + ((size_t)bh * NBUCK + ib) * 32;
  const float* k0 = sk + ((size_t)bh * NBUCK + lane) * 32;
  const float* k1 = k0 + 64 * 32;
  float s0 = 0.f, s1 = 0.f;
#pragma unroll
  for (int d = 0; d < 32; d++) {
    float qd = qrow[d];
    s0 += qd * k0[d];
    s1 += qd * k1[d];
  }
  const float sc = 0.17677669529663687f * (4.0f / 3.0f);
  float L0 = s0 * sc, L1 = s1 * sc;
  float m = fmaxf(L0, L1);
#pragma unroll
  for (int off = 32; off; off >>= 1) m = fmaxf(m, __shfl_xor(m, off));
  float Z = expf(L0 - m) + expf(L1 - m);
#pragma unroll
  for (int off = 32; off; off >>= 1) Z += __shfl_xor(Z, off);
  float mv = (L1 > L0) ? L1 : L0;
  int mj = (L1 > L0) ? lane + 64 : lane;
#pragma unroll
  for (int off = 32; off; off >>= 1) {
    float ov = __shfl_xor(mv, off);
    int oj = __shfl_xor(mj, off);
    if (ov > mv || (ov == mv && oj < mj)) { mv = ov; mj = oj; }
  }
  if (lane == 0) {
    ridx[blk] = mj;
    rw[blk] = 1.0f / Z;
  }
}

// ---------------------------------------------------------------------------
// MFMA bucketed attention reading packed qkv (ld 768). Output bf16.
// ---------------------------------------------------------------------------
__global__ __launch_bounds__(256)
void attn_mfma_k(const ushort* __restrict__ qkv,
                 const int* __restrict__ ridx, const float* __restrict__ rw,
                 ushort* __restrict__ o) {
  __shared__ ushort Qs[64][40];
  __shared__ ushort Ks[128][40];
  __shared__ ushort Vt[32][136];
  __shared__ ushort Ps[4][16][136];
  int blk = blockIdx.x;
  int bh = blk >> 7, ib = blk & 127;
  int b = bh >> 3, h = bh & 7;
  int tid = threadIdx.x;
  int jr = ridx[blk];
  float w = rw[blk];
  // stage Q
  {
    int r = tid >> 2, c = (tid & 3) << 3;
    const ushort* src = qkv + ((size_t)b * T_LEN + (size_t)ib * 64 + r) * 768 + h * 32 + c;
    *(bf16x8*)&Qs[r][c] = *(const bf16x8*)src;
  }
  // stage K
#pragma unroll
  for (int p = 0; p < 2; p++) {
    int idx = tid + (p << 8);
    int r = idx >> 2, c = (idx & 3) << 3;
    int srcb = (r < 64) ? jr : ib;
    int tt = r & 63;
    const ushort* src = qkv + ((size_t)b * T_LEN + (size_t)srcb * 64 + tt) * 768 + 256 + h * 32 + c;
    *(bf16x8*)&Ks[r][c] = *(const bf16x8*)src;
  }
  // stage V^T
  {
    int tok = tid >> 1, d0 = (tid & 1) << 4;
    int srcb = (tok < 64) ? jr : ib;
    int tt = tok & 63;
    const ushort* src = qkv + ((size_t)b * T_LEN + (size_t)srcb * 64 + tt) * 768 + 512 + h * 32 + d0;
    bf16x8 v0 = *(const bf16x8*)src;
    bf16x8 v1 = *(const bf16x8*)(src + 8);
#pragma unroll
    for (int j = 0; j < 8; j++) {
      Vt[d0 + j][tok] = (ushort)v0[j];
      Vt[d0 + 8 + j][tok] = (ushort)v1[j];
    }
  }
  __syncthreads();
  int wid = tid >> 6, lane = tid & 63, l15 = lane & 15, quad = lane >> 4;
  bf16x8 aQ = *(const bf16x8*)&Qs[(wid << 4) + l15][quad << 3];
  f32x4 sf[8];
#pragma unroll
  for (int jn = 0; jn < 8; jn++) {
    bf16x8 bK = *(const bf16x8*)&Ks[(jn << 4) + l15][quad << 3];
    f32x4 z = {0.f, 0.f, 0.f, 0.f};
    sf[jn] = __builtin_amdgcn_mfma_f32_16x16x32_bf16(aQ, bK, z, 0, 0, 0);
  }
  const float sc = 0.17677669529663687f;
#pragma unroll
  for (int jn = 0; jn < 8; jn++) {
    float mult = (jn < 4) ? w * sc : sc;
#pragma unroll
    for (int r = 0; r < 4; r++) sf[jn][r] *= mult;
  }
  float mx[4], sm[4], inv[4];
#pragma unroll
  for (int r = 0; r < 4; r++) {
    float m = sf[0][r];
#pragma unroll
    for (int jn = 1; jn < 8; jn++) m = fmaxf(m, sf[jn][r]);
    mx[r] = m;
  }
#pragma unroll
  for (int off = 1; off < 16; off <<= 1)
#pragma unroll
    for (int r = 0; r < 4; r++) mx[r] = fmaxf(mx[r], __shfl_xor(mx[r], off));
#pragma unroll
  for (int r = 0; r < 4; r++) sm[r] = 0.f;
#pragma unroll
  for (int jn = 0; jn < 8; jn++)
#pragma unroll
    for (int r = 0; r < 4; r++) {
      sf[jn][r] = expf(sf[jn][r] - mx[r]);
      sm[r] += sf[jn][r];
    }
#pragma unroll
  for (int off = 1; off < 16; off <<= 1)
#pragma unroll
    for (int r = 0; r < 4; r++) sm[r] += __shfl_xor(sm[r], off);
#pragma unroll
  for (int r = 0; r < 4; r++) inv[r] = 1.0f / sm[r];
#pragma unroll
  for (int jn = 0; jn < 8; jn++) {
    float ws2 = (jn < 4) ? w : 1.f;
#pragma unroll
    for (int r = 0; r < 4; r++)
      Ps[wid][(quad << 2) + r][(jn << 4) + l15] = f2bf(sf[jn][r] * inv[r] * ws2);
  }
  f32x4 of[2];
#pragma unroll
  for (int nd = 0; nd < 2; nd++) { f32x4 z = {0.f, 0.f, 0.f, 0.f}; of[nd] = z; }
#pragma unroll
  for (int kk = 0; kk < 4; kk++) {
    bf16x8 aP = *(const bf16x8*)&Ps[wid][l15][(kk << 5) + (quad << 3)];
#pragma unroll
    for (int nd = 0; nd < 2; nd++) {
      bf16x8 bV = *(const bf16x8*)&Vt[(nd << 4) + l15][(kk << 5) + (quad << 3)];
      of[nd] = __builtin_amdgcn_mfma_f32_16x16x32_bf16(aP, bV, of[nd], 0, 0, 0);
    }
  }
  ushort* obase = o + ((size_t)b * T_LEN + (size_t)ib * 64 + (wid << 4) + (quad << 2)) * 256 + h * 32 + l15;
#pragma unroll
  for (int nd = 0; nd < 2; nd++)
#pragma unroll
    for (int r = 0; r < 4; r++)
      obase[(size_t)r * 256 + (nd << 4)] = f2bf(of[nd][r]);
}

// ---------------------------------------------------------------------------
// out[b,d,t] = yln[b,t,d]
// ---------------------------------------------------------------------------
__global__ __launch_bounds__(256)
void transpose_out_k(const float* __restrict__ yln, float* __restrict__ out) {
  __shared__ float tile[32][33];
  int b  = blockIdx.z;
  int t0 = blockIdx.x * 32;
  int d0 = blockIdx.y * 32;
  int tx = threadIdx.x;
  int ty = threadIdx.y;
#pragma unroll
  for (int k = 0; k < 4; k++) {
    int t = t0 + ty + k * 8;
    tile[ty + k * 8][tx] = yln[((size_t)b * T_LEN + t) * DIMC + d0 + tx];
  }
  __syncthreads();
#pragma unroll
  for (int k = 0; k < 4; k++) {
    int d = d0 + ty + k * 8;
    out[((size_t)b * DIMC + d) * T_LEN + t0 + tx] = tile[tx][ty + k * 8];
  }
}

// ---------------------------------------------------------------------------
extern "C" void kernel_launch(void* const* d_in, const int* in_sizes, int n_in,
                              void* d_out, int out_size, void* d_ws, size_t ws_size,
                              hipStream_t stream) {
  const float* x     = (const float*)d_in[0];
  const float* pe0   = (const float*)d_in[1];
  const float* pe1   = (const float*)d_in[2];
  const float* ln1_g = (const float*)d_in[3];
  const float* ln1_b = (const float*)d_in[4];
  const float* Wq    = (const float*)d_in[5];
  const float* Wkv   = (const float*)d_in[6];
  const float* Wo    = (const float*)d_in[7];
  const float* bo    = (const float*)d_in[8];
  const float* ln2_g = (const float*)d_in[9];
  const float* ln2_b = (const float*)d_in[10];
  const float* W1    = (const float*)d_in[11];
  const float* b1    = (const float*)d_in[12];
  const float* W2    = (const float*)d_in[13];
  const float* b2    = (const float*)d_in[14];
  const float* gf    = (const float*)d_in[15];
  const float* bfp   = (const float*)d_in[16];
  float* out = (float*)d_out;

  const int M = MROWS;
  // workspace: y(32MB f32) | qkv(48MB bf16) | bufA(16MB) | bufB(16MB) | wbf(9MB) | stats
  float*  y    = (float*)d_ws;
  ushort* qkv  = (ushort*)(y + (size_t)M * 256);
  ushort* bufA = qkv + (size_t)M * 768;     // attn out
  ushort* bufB = bufA + (size_t)M * 256;    // LN1/LN2 out
  ushort* wbf  = bufB + (size_t)M * 256;
  float*  sqb  = (float*)(wbf + (size_t)6 * 786432);
  float*  skb  = sqb + 131072;
  float*  rwb  = skb + 131072;
  int*    rib  = (int*)(rwb + 4096);
  ushort* ffbf = qkv;  // FF intermediate (M*1024) overlays dead qkv+bufA

  dim3 tb(32, 8);
  // packed transposed weights per layer (786432 ushorts): [qkvT 768x256 | woT | w1T | w2T]
  wt_bf16_k<<<dim3(8, 8, 6),  tb, 0, stream>>>(Wq,  wbf + 0,      256, 256,  786432);
  wt_bf16_k<<<dim3(16, 8, 6), tb, 0, stream>>>(Wkv, wbf + 65536,  256, 512,  786432);
  wt_bf16_k<<<dim3(8, 8, 6),  tb, 0, stream>>>(Wo,  wbf + 196608, 256, 256,  786432);
  wt_bf16_k<<<dim3(32, 8, 6), tb, 0, stream>>>(W1,  wbf + 262144, 256, 1024, 786432);
  wt_bf16_k<<<dim3(8, 32, 6), tb, 0, stream>>>(W2,  wbf + 524288, 1024, 256, 786432);

  add_pos_k<<<dim3(T_LEN / 32, DIMC / 32, 4), tb, 0, stream>>>(x, pe0, pe1, y);
  layernorm_k<<<M / 4, 256, 0, stream>>>(y, ln1_g, ln1_b, bufB);   // layer-0 LN1

  for (int l = 0; l < 6; l++) {
    const ushort* wl    = wbf + (size_t)l * 786432;
    const ushort* wqkvT = wl;
    const ushort* woT   = wl + 196608;
    const ushort* w1T   = wl + 262144;
    const ushort* w2T   = wl + 524288;

    gemm_bf16<0><<<dim3(6, M / 128), 256, 0, stream>>>(bufB, wqkvT, nullptr, qkv, 768, 256, 256, 256);
    summary_k<<<BHEAD * NBUCK, 64, 0, stream>>>(qkv, sqb, skb);
    route_k<<<BHEAD * NBUCK, 64, 0, stream>>>(sqb, skb, rib, rwb);
    attn_mfma_k<<<BHEAD * NBUCK, 256, 0, stream>>>(qkv, rib, rwb, bufA);
    // o-proj + bias + residual + LN2 -> bufB
    gemm_fused_ln_k<0><<<M / 64, 256, 0, stream>>>(bufA, woT, bo + l * 256, y,
                                                   ln2_g + l * 256, ln2_b + l * 256,
                                                   bufB, 256, 256);
    // FF up + gelu -> ffbf (overlays qkv+bufA, both dead)
    gemm_bf16<1><<<dim3(8, M / 128), 256, 0, stream>>>(bufB, w1T, b1 + l * 1024, ffbf, 1024, 256, 256, 256);
    // FF down + bias + residual + LN (next layer's LN1, or final LN)
    if (l < 5) {
      gemm_fused_ln_k<0><<<M / 64, 256, 0, stream>>>(ffbf, w2T, b2 + l * 256, y,
                                                     ln1_g + (l + 1) * 256, ln1_b + (l + 1) * 256,
                                                     bufB, 1024, 1024);
    } else {
      gemm_fused_ln_k<1><<<M / 64, 256, 0, stream>>>(ffbf, w2T, b2 + l * 256, y,
                                                     gf, bfp, nullptr, 1024, 1024);
    }
  }

  transpose_out_k<<<dim3(T_LEN / 32, DIMC / 32, 4), tb, 0, stream>>>(y, out);

  (void)in_sizes; (void)n_in; (void)out_size; (void)ws_size;
}

// Round 6
// 1543.641 us; speedup vs baseline: 4.2356x; 1.0145x over previous
//
#include <hip/hip_runtime.h>
#include <cstdint>
#include <cstddef>

#define T_LEN 8192
#define DIMC  256
#define NBUCK 128
#define BHEAD 32
#define MROWS 32768

typedef __attribute__((ext_vector_type(8))) short bf16x8;
typedef __attribute__((ext_vector_type(4))) float f32x4;

__device__ __forceinline__ ushort f2bf(float x) {
  union { float f; unsigned u; } v; v.f = x;
  unsigned r = v.u + 0x7fffu + ((v.u >> 16) & 1u);
  return (ushort)(r >> 16);
}
__device__ __forceinline__ float bf2f(ushort u) {
  union { unsigned u; float f; } v; v.u = ((unsigned)u) << 16; return v.f;
}

__device__ __forceinline__ void gld16(const void* g, void* l) {
  __builtin_amdgcn_global_load_lds((const __attribute__((address_space(1))) void*)g,
                                   (__attribute__((address_space(3))) void*)l, 16, 0, 0);
}

// ---------------------------------------------------------------------------
// y[b,t,d] = x[b,d,t] + pe0[t/64,d] + pe1[t%64,d]
// ---------------------------------------------------------------------------
__global__ __launch_bounds__(256)
void add_pos_k(const float* __restrict__ x, const float* __restrict__ pe0,
               const float* __restrict__ pe1, float* __restrict__ y) {
  __shared__ float tile[32][33];
  int b  = blockIdx.z;
  int t0 = blockIdx.x * 32;
  int d0 = blockIdx.y * 32;
  int tj = threadIdx.x;
  int di = threadIdx.y;
#pragma unroll
  for (int k = 0; k < 4; k++) {
    int d = d0 + di + k * 8;
    tile[di + k * 8][tj] = x[((size_t)b * DIMC + d) * T_LEN + t0 + tj];
  }
  __syncthreads();
#pragma unroll
  for (int k = 0; k < 4; k++) {
    int t = t0 + di + k * 8;
    int d = d0 + tj;
    y[((size_t)b * T_LEN + t) * DIMC + d] =
        tile[tj][di + k * 8] + pe0[(size_t)(t >> 6) * DIMC + d] + pe1[(size_t)(t & 63) * DIMC + d];
  }
}

// ---------------------------------------------------------------------------
// Standalone LayerNorm (layer-0 LN1 only). Writes bf16.
// ---------------------------------------------------------------------------
__global__ __launch_bounds__(256)
void layernorm_k(const float* __restrict__ x, const float* __restrict__ g,
                 const float* __restrict__ b, ushort* __restrict__ o) {
  int row  = blockIdx.x * 4 + (threadIdx.x >> 6);
  int lane = threadIdx.x & 63;
  const float4* xr = (const float4*)(x + (size_t)row * DIMC);
  float4 v = xr[lane];
  float s  = v.x + v.y + v.z + v.w;
  float s2 = v.x * v.x + v.y * v.y + v.z * v.z + v.w * v.w;
#pragma unroll
  for (int off = 32; off; off >>= 1) {
    s  += __shfl_xor(s, off);
    s2 += __shfl_xor(s2, off);
  }
  float mean = s * (1.0f / 256.0f);
  float var  = s2 * (1.0f / 256.0f) - mean * mean;
  float r    = rsqrtf(var + 1e-5f);
  float4 gv = ((const float4*)g)[lane];
  float4 bv = ((const float4*)b)[lane];
  ushort4 o4;
  o4.x = f2bf((v.x - mean) * r * gv.x + bv.x);
  o4.y = f2bf((v.y - mean) * r * gv.y + bv.y);
  o4.z = f2bf((v.z - mean) * r * gv.z + bv.z);
  o4.w = f2bf((v.w - mean) * r * gv.w + bv.w);
  ((ushort4*)(o + (size_t)row * DIMC))[lane] = o4;
}

// ---------------------------------------------------------------------------
// weight convert: Wt[l][n][k] = bf16(W[l][k][n])
// ---------------------------------------------------------------------------
__global__ __launch_bounds__(256)
void wt_bf16_k(const float* __restrict__ W, ushort* __restrict__ Wt,
               int K, int N, size_t outStride) {
  __shared__ float t[32][33];
  int l = blockIdx.z;
  const float* Wl = W + (size_t)l * K * N;
  ushort* Wtl = Wt + (size_t)l * outStride;
  int n0 = blockIdx.x * 32, k0 = blockIdx.y * 32;
  int tx = threadIdx.x, ty = threadIdx.y;
#pragma unroll
  for (int p = 0; p < 4; p++)
    t[ty + p * 8][tx] = Wl[(size_t)(k0 + ty + p * 8) * N + n0 + tx];
  __syncthreads();
#pragma unroll
  for (int p = 0; p < 4; p++)
    Wtl[(size_t)(n0 + ty + p * 8) * K + k0 + tx] = f2bf(t[tx][ty + p * 8]);
}

// ---------------------------------------------------------------------------
// bf16 MFMA GEMM (qkv): A(MxK,lda) @ Bt(NxK,ldb)^T -> bf16
// 128x128 tile, BK=32, 256 threads (2x2 waves), 4x4 MFMA per wave.
// ---------------------------------------------------------------------------
__global__ __launch_bounds__(256)
void gemm_bf16(const ushort* __restrict__ A, const ushort* __restrict__ Bt,
               ushort* __restrict__ Cbf, int N, int K, int lda, int ldb) {
  __shared__ ushort As[128 * 32];
  __shared__ ushort Bs[128 * 32];
  int tid = threadIdx.x;
  int w = tid >> 6, lane = tid & 63;
  int bm = blockIdx.y << 7, bn = blockIdx.x << 7;
  int wm = (w >> 1) << 6, wn = (w & 1) << 6;
  int l15 = lane & 15, quad = lane >> 4;

  int off0 = (w << 11) + (lane << 4);
  int off1 = off0 + 1024;
  int r0 = off0 >> 6, c0 = (off0 & 63) >> 1;
  int r1 = off1 >> 6, c1 = (off1 & 63) >> 1;
  const ushort* ga0 = A + (size_t)(bm + r0) * lda + c0;
  const ushort* ga1 = A + (size_t)(bm + r1) * lda + c1;
  const ushort* gb0 = Bt + (size_t)(bn + r0) * ldb + c0;
  const ushort* gb1 = Bt + (size_t)(bn + r1) * ldb + c1;
  ushort* lA0 = As + (w << 10);
  ushort* lA1 = lA0 + 512;
  ushort* lB0 = Bs + (w << 10);
  ushort* lB1 = lB0 + 512;

  f32x4 acc[4][4];
#pragma unroll
  for (int i = 0; i < 4; i++)
#pragma unroll
    for (int j = 0; j < 4; j++) {
      f32x4 z = {0.f, 0.f, 0.f, 0.f};
      acc[i][j] = z;
    }

  for (int k0 = 0; k0 < K; k0 += 32) {
    gld16(ga0 + k0, lA0);
    gld16(ga1 + k0, lA1);
    gld16(gb0 + k0, lB0);
    gld16(gb1 + k0, lB1);
    __syncthreads();
    bf16x8 aF[4], bF[4];
#pragma unroll
    for (int i = 0; i < 4; i++)
      aF[i] = *(const bf16x8*)(As + ((wm + (i << 4) + l15) << 5) + (quad << 3));
#pragma unroll
    for (int j = 0; j < 4; j++)
      bF[j] = *(const bf16x8*)(Bs + ((wn + (j << 4) + l15) << 5) + (quad << 3));
#pragma unroll
    for (int i = 0; i < 4; i++)
#pragma unroll
      for (int j = 0; j < 4; j++)
        acc[i][j] = __builtin_amdgcn_mfma_f32_16x16x32_bf16(aF[i], bF[j], acc[i][j], 0, 0, 0);
    __syncthreads();
  }

#pragma unroll
  for (int j = 0; j < 4; j++) {
    int col = bn + wn + (j << 4) + l15;
#pragma unroll
    for (int i = 0; i < 4; i++) {
      int rowb = bm + wm + (i << 4) + (quad << 2);
#pragma unroll
      for (int r = 0; r < 4; r++)
        Cbf[(size_t)(rowb + r) * N + col] = f2bf(acc[i][j][r]);
    }
  }
}

// ---------------------------------------------------------------------------
// o-proj + bias + residual + LN2. 32-row blocks (grid M/32), 256 threads.
// Waves 2x2: wave = 16 rows x 128 cols (8 j-tiles). K=256.
//   v = A@Bt^T + bias + y ; y = v ; obf = bf16(LN(v))
// ---------------------------------------------------------------------------
__global__ __launch_bounds__(256)
void oproj_ln_k(const ushort* __restrict__ A, const ushort* __restrict__ Bt,
                const float* __restrict__ bias, float* __restrict__ y,
                const float* __restrict__ g, const float* __restrict__ b,
                ushort* __restrict__ obf, int K, int lda) {
  __shared__ ushort As[32 * 32];    // 2KB
  __shared__ ushort Bs[256 * 32];   // 16KB
  __shared__ float red[4][16][2];
  __shared__ float stat[32][2];
  int tid = threadIdx.x;
  int wid = tid >> 6, lane = tid & 63;
  int l15 = lane & 15, quad = lane >> 4;
  int bm = blockIdx.x << 5;
  int wm = (wid >> 1) << 4;   // 0 / 16
  int wn = (wid & 1) << 7;    // 0 / 128

  int ua = (wid << 6) + lane;          // A: waves 0,1 -> 128 units
  int ra = ua >> 2, kqa = ua & 3;
  const ushort* gaA = A + (size_t)(bm + ra) * lda + (kqa << 3);
  ushort* lAb = As + (wid << 9);
  int rb[4], kqb[4];
  const ushort* gaB[4];
  ushort* lBb[4];
#pragma unroll
  for (int p = 0; p < 4; p++) {
    int u = (p << 8) + tid;
    rb[p] = u >> 2; kqb[p] = u & 3;
    gaB[p] = Bt + (size_t)rb[p] * K + (kqb[p] << 3);
    lBb[p] = Bs + ((p << 8) + (wid << 6)) * 8;
  }

  f32x4 acc[8];
#pragma unroll
  for (int j = 0; j < 8; j++) { f32x4 z = {0.f, 0.f, 0.f, 0.f}; acc[j] = z; }

  for (int k0 = 0; k0 < K; k0 += 32) {
    if (wid < 2) gld16(gaA + k0, lAb);
#pragma unroll
    for (int p = 0; p < 4; p++) gld16(gaB[p] + k0, lBb[p]);
    __syncthreads();
    bf16x8 aF = *(const bf16x8*)(As + ((wm + l15) << 5) + (quad << 3));
#pragma unroll
    for (int j = 0; j < 8; j++) {
      bf16x8 bF = *(const bf16x8*)(Bs + ((wn + (j << 4) + l15) << 5) + (quad << 3));
      acc[j] = __builtin_amdgcn_mfma_f32_16x16x32_bf16(aF, bF, acc[j], 0, 0, 0);
    }
    __syncthreads();
  }

  float s1v[4] = {}, s2v[4] = {};
#pragma unroll
  for (int j = 0; j < 8; j++) {
    int col = wn + (j << 4) + l15;
    float bc = bias[col];
#pragma unroll
    for (int r = 0; r < 4; r++) {
      int row = bm + wm + (quad << 2) + r;
      size_t idx = (size_t)row * 256 + col;
      float v = acc[j][r] + bc + y[idx];
      acc[j][r] = v;
      y[idx] = v;
      s1v[r] += v;
      s2v[r] += v * v;
    }
  }
#pragma unroll
  for (int off = 1; off < 16; off <<= 1)
#pragma unroll
    for (int r = 0; r < 4; r++) {
      s1v[r] += __shfl_xor(s1v[r], off);
      s2v[r] += __shfl_xor(s2v[r], off);
    }
  if (l15 == 0) {
#pragma unroll
    for (int r = 0; r < 4; r++) {
      red[wid][(quad << 2) + r][0] = s1v[r];
      red[wid][(quad << 2) + r][1] = s2v[r];
    }
  }
  __syncthreads();
  if (tid < 32) {
    int rr = tid;
    float s, s2;
    if (rr < 16) { s = red[0][rr][0] + red[1][rr][0]; s2 = red[0][rr][1] + red[1][rr][1]; }
    else { s = red[2][rr - 16][0] + red[3][rr - 16][0]; s2 = red[2][rr - 16][1] + red[3][rr - 16][1]; }
    float mean = s * (1.0f / 256.0f);
    float var  = s2 * (1.0f / 256.0f) - mean * mean;
    stat[rr][0] = mean;
    stat[rr][1] = rsqrtf(var + 1e-5f);
  }
  __syncthreads();
#pragma unroll
  for (int j = 0; j < 8; j++) {
    int col = wn + (j << 4) + l15;
    float gc = g[col], bc2 = b[col];
#pragma unroll
    for (int r = 0; r < 4; r++) {
      int lr = wm + (quad << 2) + r;
      float o = (acc[j][r] - stat[lr][0]) * stat[lr][1] * gc + bc2;
      obf[(size_t)(bm + lr) * 256 + col] = f2bf(o);
    }
  }
}

// ---------------------------------------------------------------------------
// Fused FF block: v = gelu(A@W1+b1)@W2 + b2 + y ; y=v ; obf = LN(v) (bf16)
// FINAL: y = LN(v) (fp32), no obf/residual store.
// 64-row blocks, 4 waves; wave owns 16 rows, full 256 cols.
// A-fragments in registers; 32 ff-chunks of 32 streamed via LDS.
// W1 chunk = 32n x 256k = 16KB = 4 gld16 sites; W2 chunk = 256n x 32k = 4 sites.
// ---------------------------------------------------------------------------
template <int FINAL>
__global__ __launch_bounds__(256)
void ff_fused_k(const ushort* __restrict__ A, const ushort* __restrict__ w1T,
                const ushort* __restrict__ w2T, const float* __restrict__ b1,
                const float* __restrict__ b2, float* __restrict__ y,
                const float* __restrict__ g, const float* __restrict__ bvec,
                ushort* __restrict__ obf) {
  __shared__ ushort W1s[8 * 32 * 32];   // [kk][n][klocal] 16KB
  __shared__ ushort W2s[256 * 32];      // [n][klocal] 16KB
  __shared__ ushort Ss[4 * 16 * 40];    // per-wave s tiles, pad 40
  int tid = threadIdx.x;
  int wid = tid >> 6, lane = tid & 63;
  int l15 = lane & 15, quad = lane >> 4;
  int bm = blockIdx.x << 6;
  int row0 = bm + (wid << 4);

  // A-fragments in registers (wave's 16 rows x K=256)
  bf16x8 aF[8];
  const ushort* arow = A + (size_t)(row0 + l15) * 256 + (quad << 3);
#pragma unroll
  for (int kk = 0; kk < 8; kk++) aF[kk] = *(const bf16x8*)(arow + (kk << 5));

  // staging: p<4 -> W1s (1024 units), p>=4 -> W2s (1024 units)
  const ushort* gsrc[8];
  ushort* ldst[8];
#pragma unroll
  for (int p = 0; p < 8; p++) {
    if (p < 4) {
      int u = (p << 8) + (wid << 6) + lane;
      int kk = u >> 7, n = (u >> 2) & 31, kq = u & 3;
      gsrc[p] = w1T + (size_t)n * 256 + kk * 32 + (kq << 3);   // + c*8192 later
      ldst[p] = W1s + ((p << 8) + (wid << 6)) * 8;
    } else {
      int v2 = ((p - 4) << 8) + (wid << 6) + lane;
      int n = v2 >> 2, kq = v2 & 3;
      gsrc[p] = w2T + (size_t)n * 1024 + (kq << 3);            // + c*32 later
      ldst[p] = W2s + (((p - 4) << 8) + (wid << 6)) * 8;
    }
  }

  f32x4 vacc[16];
#pragma unroll
  for (int j = 0; j < 16; j++) { f32x4 z = {0.f, 0.f, 0.f, 0.f}; vacc[j] = z; }

  ushort* sW = Ss + wid * 640;

  for (int c = 0; c < 32; c++) {
    gld16(gsrc[0] + (size_t)c * 8192, ldst[0]);
    gld16(gsrc[1] + (size_t)c * 8192, ldst[1]);
    gld16(gsrc[2] + (size_t)c * 8192, ldst[2]);
    gld16(gsrc[3] + (size_t)c * 8192, ldst[3]);
    gld16(gsrc[4] + c * 32, ldst[4]);
    gld16(gsrc[5] + c * 32, ldst[5]);
    gld16(gsrc[6] + c * 32, ldst[6]);
    gld16(gsrc[7] + c * 32, ldst[7]);
    __syncthreads();
    // FF1: s(16x32) = gelu(A @ W1c^T + b1)
#pragma unroll
    for (int jn = 0; jn < 2; jn++) {
      f32x4 sf = {0.f, 0.f, 0.f, 0.f};
#pragma unroll
      for (int kk = 0; kk < 8; kk++) {
        bf16x8 bF = *(const bf16x8*)&W1s[(kk << 10) + (((jn << 4) + l15) << 5) + (quad << 3)];
        sf = __builtin_amdgcn_mfma_f32_16x16x32_bf16(aF[kk], bF, sf, 0, 0, 0);
      }
      float bb = b1[(c << 5) + (jn << 4) + l15];
#pragma unroll
      for (int r = 0; r < 4; r++) {
        float v = sf[r] + bb;
        v = 0.5f * v * (1.0f + erff(v * 0.70710678118654752f));
        sW[((quad << 2) + r) * 40 + (jn << 4) + l15] = f2bf(v);
      }
    }
    // FF2: vacc(16x256) += s @ W2c^T (wave-local s)
    bf16x8 aP = *(const bf16x8*)&sW[l15 * 40 + (quad << 3)];
#pragma unroll
    for (int j = 0; j < 16; j++) {
      bf16x8 bF = *(const bf16x8*)&W2s[(((j << 4) + l15) << 5) + (quad << 3)];
      vacc[j] = __builtin_amdgcn_mfma_f32_16x16x32_bf16(aP, bF, vacc[j], 0, 0, 0);
    }
    __syncthreads();
  }

  // epilogue: v = vacc + b2 + y ; LN over wave-owned full rows
  float s1v[4] = {}, s2v[4] = {};
#pragma unroll
  for (int j = 0; j < 16; j++) {
    int col = (j << 4) + l15;
    float bc = b2[col];
#pragma unroll
    for (int r = 0; r < 4; r++) {
      int row = row0 + (quad << 2) + r;
      size_t idx = (size_t)row * 256 + col;
      float v = vacc[j][r] + bc + y[idx];
      vacc[j][r] = v;
      if (!FINAL) y[idx] = v;
      s1v[r] += v;
      s2v[r] += v * v;
    }
  }
#pragma unroll
  for (int off = 1; off < 16; off <<= 1)
#pragma unroll
    for (int r = 0; r < 4; r++) {
      s1v[r] += __shfl_xor(s1v[r], off);
      s2v[r] += __shfl_xor(s2v[r], off);
    }
  float mean[4], rstd[4];
#pragma unroll
  for (int r = 0; r < 4; r++) {
    mean[r] = s1v[r] * (1.0f / 256.0f);
    float var = s2v[r] * (1.0f / 256.0f) - mean[r] * mean[r];
    rstd[r] = rsqrtf(var + 1e-5f);
  }
#pragma unroll
  for (int j = 0; j < 16; j++) {
    int col = (j << 4) + l15;
    float gc = g[col], bc2 = bvec[col];
#pragma unroll
    for (int r = 0; r < 4; r++) {
      int row = row0 + (quad << 2) + r;
      size_t idx = (size_t)row * 256 + col;
      float o = (vacc[j][r] - mean[r]) * rstd[r] * gc + bc2;
      if (FINAL) y[idx] = o;
      else obf[idx] = f2bf(o);
    }
  }
}

// ---------------------------------------------------------------------------
// bucket summaries from packed qkv (ld 768): q at +0, k at +256
// ---------------------------------------------------------------------------
__global__ __launch_bounds__(64)
void summary_k(const ushort* __restrict__ qkv,
               float* __restrict__ sq, float* __restrict__ sk) {
  int blk = blockIdx.x;
  int bh = blk >> 7, ib = blk & 127;
  int b = bh >> 3, h = bh & 7;
  int lane = threadIdx.x;
  int d = lane & 31;
  bool isK = lane >= 32;
  size_t base = ((size_t)b * T_LEN + (size_t)ib * 64) * 768 + (isK ? 256 : 0) + h * 32 + d;
  float s = 0.f;
#pragma unroll 8
  for (int t = 0; t < 64; t++) s += bf2f(qkv[base + (size_t)t * 768]);
  s *= (1.0f / 64.0f);
  float* dst = isK ? sk : sq;
  dst[((size_t)bh * NBUCK + ib) * 32 + d] = s;
}

// ---------------------------------------------------------------------------
// routing
// ---------------------------------------------------------------------------
__global__ __launch_bounds__(64)
void route_k(const float* __restrict__ sq, const float* __restrict__ sk,
             int* __restrict__ ridx, float* __restrict__ rw) {
  int blk = blockIdx.x;
  int bh = blk >> 7, ib = blk & 127;
  int lane = threadIdx.x;
  const float* qrow = sq + ((size_t)bh * NBUCK + ib) * 32;
  const float* k0 = sk + ((size_t)bh * NBUCK + lane) * 32;
  const float* k1 = k0 + 64 * 32;
  float s0 = 0.f, s1 = 0.f;
#pragma unroll
  for (int d = 0; d < 32; d++) {
    float qd = qrow[d];
    s0 += qd * k0[d];
    s1 += qd * k1[d];
  }
  const float sc = 0.17677669529663687f * (4.0f / 3.0f);
  float L0 = s0 * sc, L1 = s1 * sc;
  float m = fmaxf(L0, L1);
#pragma unroll
  for (int off = 32; off; off >>= 1) m = fmaxf(m, __shfl_xor(m, off));
  float Z = expf(L0 - m) + expf(L1 - m);
#pragma unroll
  for (int off = 32; off; off >>= 1) Z += __shfl_xor(Z, off);
  float mv = (L1 > L0) ? L1 : L0;
  int mj = (L1 > L0) ? lane + 64 : lane;
#pragma unroll
  for (int off = 32; off; off >>= 1) {
    float ov = __shfl_xor(mv, off);
    int oj = __shfl_xor(mj, off);
    if (ov > mv || (ov == mv && oj < mj)) { mv = ov; mj = oj; }
  }
  if (lane == 0) {
    ridx[blk] = mj;
    rw[blk] = 1.0f / Z;
  }
}

// ---------------------------------------------------------------------------
// MFMA bucketed attention reading packed qkv (ld 768). Output bf16.
// ---------------------------------------------------------------------------
__global__ __launch_bounds__(256)
void attn_mfma_k(const ushort* __restrict__ qkv,
                 const int* __restrict__ ridx, const float* __restrict__ rw,
                 ushort* __restrict__ o) {
  __shared__ ushort Qs[64][40];
  __shared__ ushort Ks[128][40];
  __shared__ ushort Vt[32][136];
  __shared__ ushort Ps[4][16][136];
  int blk = blockIdx.x;
  int bh = blk >> 7, ib = blk & 127;
  int b = bh >> 3, h = bh & 7;
  int tid = threadIdx.x;
  int jr = ridx[blk];
  float w = rw[blk];
  {
    int r = tid >> 2, c = (tid & 3) << 3;
    const ushort* src = qkv + ((size_t)b * T_LEN + (size_t)ib * 64 + r) * 768 + h * 32 + c;
    *(bf16x8*)&Qs[r][c] = *(const bf16x8*)src;
  }
#pragma unroll
  for (int p = 0; p < 2; p++) {
    int idx = tid + (p << 8);
    int r = idx >> 2, c = (idx & 3) << 3;
    int srcb = (r < 64) ? jr : ib;
    int tt = r & 63;
    const ushort* src = qkv + ((size_t)b * T_LEN + (size_t)srcb * 64 + tt) * 768 + 256 + h * 32 + c;
    *(bf16x8*)&Ks[r][c] = *(const bf16x8*)src;
  }
  {
    int tok = tid >> 1, d0 = (tid & 1) << 4;
    int srcb = (tok < 64) ? jr : ib;
    int tt = tok & 63;
    const ushort* src = qkv + ((size_t)b * T_LEN + (size_t)srcb * 64 + tt) * 768 + 512 + h * 32 + d0;
    bf16x8 v0 = *(const bf16x8*)src;
    bf16x8 v1 = *(const bf16x8*)(src + 8);
#pragma unroll
    for (int j = 0; j < 8; j++) {
      Vt[d0 + j][tok] = (ushort)v0[j];
      Vt[d0 + 8 + j][tok] = (ushort)v1[j];
    }
  }
  __syncthreads();
  int wid = tid >> 6, lane = tid & 63, l15 = lane & 15, quad = lane >> 4;
  bf16x8 aQ = *(const bf16x8*)&Qs[(wid << 4) + l15][quad << 3];
  f32x4 sf[8];
#pragma unroll
  for (int jn = 0; jn < 8; jn++) {
    bf16x8 bK = *(const bf16x8*)&Ks[(jn << 4) + l15][quad << 3];
    f32x4 z = {0.f, 0.f, 0.f, 0.f};
    sf[jn] = __builtin_amdgcn_mfma_f32_16x16x32_bf16(aQ, bK, z, 0, 0, 0);
  }
  const float sc = 0.17677669529663687f;
#pragma unroll
  for (int jn = 0; jn < 8; jn++) {
    float mult = (jn < 4) ? w * sc : sc;
#pragma unroll
    for (int r = 0; r < 4; r++) sf[jn][r] *= mult;
  }
  float mx[4], sm[4], inv[4];
#pragma unroll
  for (int r = 0; r < 4; r++) {
    float m = sf[0][r];
#pragma unroll
    for (int jn = 1; jn < 8; jn++) m = fmaxf(m, sf[jn][r]);
    mx[r] = m;
  }
#pragma unroll
  for (int off = 1; off < 16; off <<= 1)
#pragma unroll
    for (int r = 0; r < 4; r++) mx[r] = fmaxf(mx[r], __shfl_xor(mx[r], off));
#pragma unroll
  for (int r = 0; r < 4; r++) sm[r] = 0.f;
#pragma unroll
  for (int jn = 0; jn < 8; jn++)
#pragma unroll
    for (int r = 0; r < 4; r++) {
      sf[jn][r] = expf(sf[jn][r] - mx[r]);
      sm[r] += sf[jn][r];
    }
#pragma unroll
  for (int off = 1; off < 16; off <<= 1)
#pragma unroll
    for (int r = 0; r < 4; r++) sm[r] += __shfl_xor(sm[r], off);
#pragma unroll
  for (int r = 0; r < 4; r++) inv[r] = 1.0f / sm[r];
#pragma unroll
  for (int jn = 0; jn < 8; jn++) {
    float ws2 = (jn < 4) ? w : 1.f;
#pragma unroll
    for (int r = 0; r < 4; r++)
      Ps[wid][(quad << 2) + r][(jn << 4) + l15] = f2bf(sf[jn][r] * inv[r] * ws2);
  }
  f32x4 of[2];
#pragma unroll
  for (int nd = 0; nd < 2; nd++) { f32x4 z = {0.f, 0.f, 0.f, 0.f}; of[nd] = z; }
#pragma unroll
  for (int kk = 0; kk < 4; kk++) {
    bf16x8 aP = *(const bf16x8*)&Ps[wid][l15][(kk << 5) + (quad << 3)];
#pragma unroll
    for (int nd = 0; nd < 2; nd++) {
      bf16x8 bV = *(const bf16x8*)&Vt[(nd << 4) + l15][(kk << 5) + (quad << 3)];
      of[nd] = __builtin_amdgcn_mfma_f32_16x16x32_bf16(aP, bV, of[nd], 0, 0, 0);
    }
  }
  ushort* obase = o + ((size_t)b * T_LEN + (size_t)ib * 64 + (wid << 4) + (quad << 2)) * 256 + h * 32 + l15;
#pragma unroll
  for (int nd = 0; nd < 2; nd++)
#pragma unroll
    for (int r = 0; r < 4; r++)
      obase[(size_t)r * 256 + (nd << 4)] = f2bf(of[nd][r]);
}

// ---------------------------------------------------------------------------
// out[b,d,t] = yln[b,t,d]
// ---------------------------------------------------------------------------
__global__ __launch_bounds__(256)
void transpose_out_k(const float* __restrict__ yln, float* __restrict__ out) {
  __shared__ float tile[32][33];
  int b  = blockIdx.z;
  int t0 = blockIdx.x * 32;
  int d0 = blockIdx.y * 32;
  int tx = threadIdx.x;
  int ty = threadIdx.y;
#pragma unroll
  for (int k = 0; k < 4; k++) {
    int t = t0 + ty + k * 8;
    tile[ty + k * 8][tx] = yln[((size_t)b * T_LEN + t) * DIMC + d0 + tx];
  }
  __syncthreads();
#pragma unroll
  for (int k = 0; k < 4; k++) {
    int d = d0 + ty + k * 8;
    out[((size_t)b * DIMC + d) * T_LEN + t0 + tx] = tile[tx][ty + k * 8];
  }
}

// ---------------------------------------------------------------------------
extern "C" void kernel_launch(void* const* d_in, const int* in_sizes, int n_in,
                              void* d_out, int out_size, void* d_ws, size_t ws_size,
                              hipStream_t stream) {
  const float* x     = (const float*)d_in[0];
  const float* pe0   = (const float*)d_in[1];
  const float* pe1   = (const float*)d_in[2];
  const float* ln1_g = (const float*)d_in[3];
  const float* ln1_b = (const float*)d_in[4];
  const float* Wq    = (const float*)d_in[5];
  const float* Wkv   = (const float*)d_in[6];
  const float* Wo    = (const float*)d_in[7];
  const float* bo    = (const float*)d_in[8];
  const float* ln2_g = (const float*)d_in[9];
  const float* ln2_b = (const float*)d_in[10];
  const float* W1    = (const float*)d_in[11];
  const float* b1    = (const float*)d_in[12];
  const float* W2    = (const float*)d_in[13];
  const float* b2    = (const float*)d_in[14];
  const float* gf    = (const float*)d_in[15];
  const float* bfp   = (const float*)d_in[16];
  float* out = (float*)d_out;

  const int M = MROWS;
  float*  y    = (float*)d_ws;                       // M*256 f32
  ushort* qkv  = (ushort*)(y + (size_t)M * 256);     // M*768 bf16
  ushort* bufA = qkv + (size_t)M * 768;              // attn out (bf16)
  ushort* bufB = bufA + (size_t)M * 256;             // LN out (bf16)
  ushort* wbf  = bufB + (size_t)M * 256;             // 6*786432 transposed weights
  float*  sqb  = (float*)(wbf + (size_t)6 * 786432);
  float*  skb  = sqb + 131072;
  float*  rwb  = skb + 131072;
  int*    rib  = (int*)(rwb + 4096);

  dim3 tb(32, 8);
  wt_bf16_k<<<dim3(8, 8, 6),  tb, 0, stream>>>(Wq,  wbf + 0,      256, 256,  786432);
  wt_bf16_k<<<dim3(16, 8, 6), tb, 0, stream>>>(Wkv, wbf + 65536,  256, 512,  786432);
  wt_bf16_k<<<dim3(8, 8, 6),  tb, 0, stream>>>(Wo,  wbf + 196608, 256, 256,  786432);
  wt_bf16_k<<<dim3(32, 8, 6), tb, 0, stream>>>(W1,  wbf + 262144, 256, 1024, 786432);
  wt_bf16_k<<<dim3(8, 32, 6), tb, 0, stream>>>(W2,  wbf + 524288, 1024, 256, 786432);

  add_pos_k<<<dim3(T_LEN / 32, DIMC / 32, 4), tb, 0, stream>>>(x, pe0, pe1, y);
  layernorm_k<<<M / 4, 256, 0, stream>>>(y, ln1_g, ln1_b, bufB);   // layer-0 LN1

  for (int l = 0; l < 6; l++) {
    const ushort* wl    = wbf + (size_t)l * 786432;
    const ushort* wqkvT = wl;
    const ushort* woT   = wl + 196608;
    const ushort* w1T   = wl + 262144;
    const ushort* w2T   = wl + 524288;

    gemm_bf16<<<dim3(6, M / 128), 256, 0, stream>>>(bufB, wqkvT, qkv, 768, 256, 256, 256);
    summary_k<<<BHEAD * NBUCK, 64, 0, stream>>>(qkv, sqb, skb);
    route_k<<<BHEAD * NBUCK, 64, 0, stream>>>(sqb, skb, rib, rwb);
    attn_mfma_k<<<BHEAD * NBUCK, 256, 0, stream>>>(qkv, rib, rwb, bufA);
    oproj_ln_k<<<M / 32, 256, 0, stream>>>(bufA, woT, bo + l * 256, y,
                                           ln2_g + l * 256, ln2_b + l * 256,
                                           bufB, 256, 256);
    if (l < 5) {
      ff_fused_k<0><<<M / 64, 256, 0, stream>>>(bufB, w1T, w2T, b1 + l * 1024,
                                                b2 + l * 256, y,
                                                ln1_g + (l + 1) * 256, ln1_b + (l + 1) * 256,
                                                bufB);
    } else {
      ff_fused_k<1><<<M / 64, 256, 0, stream>>>(bufB, w1T, w2T, b1 + l * 1024,
                                                b2 + l * 256, y, gf, bfp, nullptr);
    }
  }

  transpose_out_k<<<dim3(T_LEN / 32, DIMC / 32, 4), tb, 0, stream>>>(y, out);

  (void)in_sizes; (void)n_in; (void)out_size; (void)ws_size;
}

// Round 7
// 1453.359 us; speedup vs baseline: 4.4988x; 1.0621x over previous
//
#include <hip/hip_runtime.h>
#include <cstdint>
#include <cstddef>

#define T_LEN 8192
#define DIMC  256
#define NBUCK 128
#define BHEAD 32
#define MROWS 32768

typedef __attribute__((ext_vector_type(8))) short bf16x8;
typedef __attribute__((ext_vector_type(4))) float f32x4;

__device__ __forceinline__ ushort f2bf(float x) {
  union { float f; unsigned u; } v; v.f = x;
  unsigned r = v.u + 0x7fffu + ((v.u >> 16) & 1u);
  return (ushort)(r >> 16);
}
__device__ __forceinline__ float bf2f(ushort u) {
  union { unsigned u; float f; } v; v.u = ((unsigned)u) << 16; return v.f;
}

__device__ __forceinline__ void gld16(const void* g, void* l) {
  __builtin_amdgcn_global_load_lds((const __attribute__((address_space(1))) void*)g,
                                   (__attribute__((address_space(3))) void*)l, 16, 0, 0);
}

// ---------------------------------------------------------------------------
// y[b,t,d] = x[b,d,t] + pe0[t/64,d] + pe1[t%64,d]
// ---------------------------------------------------------------------------
__global__ __launch_bounds__(256)
void add_pos_k(const float* __restrict__ x, const float* __restrict__ pe0,
               const float* __restrict__ pe1, float* __restrict__ y) {
  __shared__ float tile[32][33];
  int b  = blockIdx.z;
  int t0 = blockIdx.x * 32;
  int d0 = blockIdx.y * 32;
  int tj = threadIdx.x;
  int di = threadIdx.y;
#pragma unroll
  for (int k = 0; k < 4; k++) {
    int d = d0 + di + k * 8;
    tile[di + k * 8][tj] = x[((size_t)b * DIMC + d) * T_LEN + t0 + tj];
  }
  __syncthreads();
#pragma unroll
  for (int k = 0; k < 4; k++) {
    int t = t0 + di + k * 8;
    int d = d0 + tj;
    y[((size_t)b * T_LEN + t) * DIMC + d] =
        tile[tj][di + k * 8] + pe0[(size_t)(t >> 6) * DIMC + d] + pe1[(size_t)(t & 63) * DIMC + d];
  }
}

// ---------------------------------------------------------------------------
// Standalone LayerNorm (layer-0 LN1 only). Writes bf16.
// ---------------------------------------------------------------------------
__global__ __launch_bounds__(256)
void layernorm_k(const float* __restrict__ x, const float* __restrict__ g,
                 const float* __restrict__ b, ushort* __restrict__ o) {
  int row  = blockIdx.x * 4 + (threadIdx.x >> 6);
  int lane = threadIdx.x & 63;
  const float4* xr = (const float4*)(x + (size_t)row * DIMC);
  float4 v = xr[lane];
  float s  = v.x + v.y + v.z + v.w;
  float s2 = v.x * v.x + v.y * v.y + v.z * v.z + v.w * v.w;
#pragma unroll
  for (int off = 32; off; off >>= 1) {
    s  += __shfl_xor(s, off);
    s2 += __shfl_xor(s2, off);
  }
  float mean = s * (1.0f / 256.0f);
  float var  = s2 * (1.0f / 256.0f) - mean * mean;
  float r    = rsqrtf(var + 1e-5f);
  float4 gv = ((const float4*)g)[lane];
  float4 bv = ((const float4*)b)[lane];
  ushort4 o4;
  o4.x = f2bf((v.x - mean) * r * gv.x + bv.x);
  o4.y = f2bf((v.y - mean) * r * gv.y + bv.y);
  o4.z = f2bf((v.z - mean) * r * gv.z + bv.z);
  o4.w = f2bf((v.w - mean) * r * gv.w + bv.w);
  ((ushort4*)(o + (size_t)row * DIMC))[lane] = o4;
}

// ---------------------------------------------------------------------------
// weight convert: Wt[l][n][k] = bf16(W[l][k][n])
// ---------------------------------------------------------------------------
__global__ __launch_bounds__(256)
void wt_bf16_k(const float* __restrict__ W, ushort* __restrict__ Wt,
               int K, int N, size_t outStride) {
  __shared__ float t[32][33];
  int l = blockIdx.z;
  const float* Wl = W + (size_t)l * K * N;
  ushort* Wtl = Wt + (size_t)l * outStride;
  int n0 = blockIdx.x * 32, k0 = blockIdx.y * 32;
  int tx = threadIdx.x, ty = threadIdx.y;
#pragma unroll
  for (int p = 0; p < 4; p++)
    t[ty + p * 8][tx] = Wl[(size_t)(k0 + ty + p * 8) * N + n0 + tx];
  __syncthreads();
#pragma unroll
  for (int p = 0; p < 4; p++)
    Wtl[(size_t)(n0 + ty + p * 8) * K + k0 + tx] = f2bf(t[tx][ty + p * 8]);
}

// ---------------------------------------------------------------------------
// bf16 MFMA GEMM: epi(A(MxK,lda) @ Bt(NxK,ldb)^T [+bias]) -> bf16
// EPI 0: store. EPI 1: gelu(.+bias).
// 128x128 tile, BK=32, 256 threads (2x2 waves), 4x4 MFMA per wave.
// ---------------------------------------------------------------------------
template <int EPI>
__global__ __launch_bounds__(256)
void gemm_bf16(const ushort* __restrict__ A, const ushort* __restrict__ Bt,
               const float* __restrict__ bias, ushort* __restrict__ Cbf,
               int N, int K, int lda, int ldb) {
  __shared__ ushort As[128 * 32];
  __shared__ ushort Bs[128 * 32];
  int tid = threadIdx.x;
  int w = tid >> 6, lane = tid & 63;
  int bm = blockIdx.y << 7, bn = blockIdx.x << 7;
  int wm = (w >> 1) << 6, wn = (w & 1) << 6;
  int l15 = lane & 15, quad = lane >> 4;

  int off0 = (w << 11) + (lane << 4);
  int off1 = off0 + 1024;
  int r0 = off0 >> 6, c0 = (off0 & 63) >> 1;
  int r1 = off1 >> 6, c1 = (off1 & 63) >> 1;
  const ushort* ga0 = A + (size_t)(bm + r0) * lda + c0;
  const ushort* ga1 = A + (size_t)(bm + r1) * lda + c1;
  const ushort* gb0 = Bt + (size_t)(bn + r0) * ldb + c0;
  const ushort* gb1 = Bt + (size_t)(bn + r1) * ldb + c1;
  ushort* lA0 = As + (w << 10);
  ushort* lA1 = lA0 + 512;
  ushort* lB0 = Bs + (w << 10);
  ushort* lB1 = lB0 + 512;

  f32x4 acc[4][4];
#pragma unroll
  for (int i = 0; i < 4; i++)
#pragma unroll
    for (int j = 0; j < 4; j++) {
      f32x4 z = {0.f, 0.f, 0.f, 0.f};
      acc[i][j] = z;
    }

  for (int k0 = 0; k0 < K; k0 += 32) {
    gld16(ga0 + k0, lA0);
    gld16(ga1 + k0, lA1);
    gld16(gb0 + k0, lB0);
    gld16(gb1 + k0, lB1);
    __syncthreads();
    bf16x8 aF[4], bF[4];
#pragma unroll
    for (int i = 0; i < 4; i++)
      aF[i] = *(const bf16x8*)(As + ((wm + (i << 4) + l15) << 5) + (quad << 3));
#pragma unroll
    for (int j = 0; j < 4; j++)
      bF[j] = *(const bf16x8*)(Bs + ((wn + (j << 4) + l15) << 5) + (quad << 3));
#pragma unroll
    for (int i = 0; i < 4; i++)
#pragma unroll
      for (int j = 0; j < 4; j++)
        acc[i][j] = __builtin_amdgcn_mfma_f32_16x16x32_bf16(aF[i], bF[j], acc[i][j], 0, 0, 0);
    __syncthreads();
  }

#pragma unroll
  for (int j = 0; j < 4; j++) {
    int col = bn + wn + (j << 4) + l15;
    float bv = (EPI == 1) ? bias[col] : 0.f;
#pragma unroll
    for (int i = 0; i < 4; i++) {
      int rowb = bm + wm + (i << 4) + (quad << 2);
#pragma unroll
      for (int r = 0; r < 4; r++) {
        float v = acc[i][j][r];
        if (EPI == 1) {
          v += bv;
          v = 0.5f * v * (1.0f + erff(v * 0.70710678118654752f));
        }
        Cbf[(size_t)(rowb + r) * N + col] = f2bf(v);
      }
    }
  }
}

// ---------------------------------------------------------------------------
// GEMM + bias + residual + LayerNorm. 32-row blocks (grid M/32), 256 threads.
// Waves 2x2: wave = 16 rows x 128 cols. Generic K (multiple of 32).
//   v = A@Bt^T + bias + y
//   FINAL=0: y = v ; obf = bf16(LN(v))
//   FINAL=1: y = LN(v) (fp32 final)
// ---------------------------------------------------------------------------
template <int FINAL>
__global__ __launch_bounds__(256)
void oproj_ln_k(const ushort* __restrict__ A, const ushort* __restrict__ Bt,
                const float* __restrict__ bias, float* __restrict__ y,
                const float* __restrict__ g, const float* __restrict__ b,
                ushort* __restrict__ obf, int K, int lda) {
  __shared__ ushort As[32 * 32];    // 2KB
  __shared__ ushort Bs[256 * 32];   // 16KB
  __shared__ float red[4][16][2];
  __shared__ float stat[32][2];
  int tid = threadIdx.x;
  int wid = tid >> 6, lane = tid & 63;
  int l15 = lane & 15, quad = lane >> 4;
  int bm = blockIdx.x << 5;
  int wm = (wid >> 1) << 4;   // 0 / 16
  int wn = (wid & 1) << 7;    // 0 / 128

  int ua = (wid << 6) + lane;          // A: waves 0,1 -> 128 units
  int ra = ua >> 2, kqa = ua & 3;
  const ushort* gaA = A + (size_t)(bm + ra) * lda + (kqa << 3);
  ushort* lAb = As + (wid << 9);
  const ushort* gaB[4];
  ushort* lBb[4];
#pragma unroll
  for (int p = 0; p < 4; p++) {
    int u = (p << 8) + tid;
    gaB[p] = Bt + (size_t)(u >> 2) * K + ((u & 3) << 3);
    lBb[p] = Bs + ((p << 8) + (wid << 6)) * 8;
  }

  f32x4 acc[8];
#pragma unroll
  for (int j = 0; j < 8; j++) { f32x4 z = {0.f, 0.f, 0.f, 0.f}; acc[j] = z; }

  for (int k0 = 0; k0 < K; k0 += 32) {
    if (wid < 2) gld16(gaA + k0, lAb);
#pragma unroll
    for (int p = 0; p < 4; p++) gld16(gaB[p] + k0, lBb[p]);
    __syncthreads();
    bf16x8 aF = *(const bf16x8*)(As + ((wm + l15) << 5) + (quad << 3));
#pragma unroll
    for (int j = 0; j < 8; j++) {
      bf16x8 bF = *(const bf16x8*)(Bs + ((wn + (j << 4) + l15) << 5) + (quad << 3));
      acc[j] = __builtin_amdgcn_mfma_f32_16x16x32_bf16(aF, bF, acc[j], 0, 0, 0);
    }
    __syncthreads();
  }

  float s1v[4] = {}, s2v[4] = {};
#pragma unroll
  for (int j = 0; j < 8; j++) {
    int col = wn + (j << 4) + l15;
    float bc = bias[col];
#pragma unroll
    for (int r = 0; r < 4; r++) {
      int row = bm + wm + (quad << 2) + r;
      size_t idx = (size_t)row * 256 + col;
      float v = acc[j][r] + bc + y[idx];
      acc[j][r] = v;
      if (!FINAL) y[idx] = v;
      s1v[r] += v;
      s2v[r] += v * v;
    }
  }
#pragma unroll
  for (int off = 1; off < 16; off <<= 1)
#pragma unroll
    for (int r = 0; r < 4; r++) {
      s1v[r] += __shfl_xor(s1v[r], off);
      s2v[r] += __shfl_xor(s2v[r], off);
    }
  if (l15 == 0) {
#pragma unroll
    for (int r = 0; r < 4; r++) {
      red[wid][(quad << 2) + r][0] = s1v[r];
      red[wid][(quad << 2) + r][1] = s2v[r];
    }
  }
  __syncthreads();
  if (tid < 32) {
    int rr = tid;
    float s, s2;
    if (rr < 16) { s = red[0][rr][0] + red[1][rr][0]; s2 = red[0][rr][1] + red[1][rr][1]; }
    else { s = red[2][rr - 16][0] + red[3][rr - 16][0]; s2 = red[2][rr - 16][1] + red[3][rr - 16][1]; }
    float mean = s * (1.0f / 256.0f);
    float var  = s2 * (1.0f / 256.0f) - mean * mean;
    stat[rr][0] = mean;
    stat[rr][1] = rsqrtf(var + 1e-5f);
  }
  __syncthreads();
#pragma unroll
  for (int j = 0; j < 8; j++) {
    int col = wn + (j << 4) + l15;
    float gc = g[col], bc2 = b[col];
#pragma unroll
    for (int r = 0; r < 4; r++) {
      int lr = wm + (quad << 2) + r;
      float o = (acc[j][r] - stat[lr][0]) * stat[lr][1] * gc + bc2;
      size_t idx = (size_t)(bm + lr) * 256 + col;
      if (FINAL) y[idx] = o;
      else obf[idx] = f2bf(o);
    }
  }
}

// ---------------------------------------------------------------------------
// bucket summaries from packed qkv (ld 768): q at +0, k at +256
// ---------------------------------------------------------------------------
__global__ __launch_bounds__(64)
void summary_k(const ushort* __restrict__ qkv,
               float* __restrict__ sq, float* __restrict__ sk) {
  int blk = blockIdx.x;
  int bh = blk >> 7, ib = blk & 127;
  int b = bh >> 3, h = bh & 7;
  int lane = threadIdx.x;
  int d = lane & 31;
  bool isK = lane >= 32;
  size_t base = ((size_t)b * T_LEN + (size_t)ib * 64) * 768 + (isK ? 256 : 0) + h * 32 + d;
  float s = 0.f;
#pragma unroll 8
  for (int t = 0; t < 64; t++) s += bf2f(qkv[base + (size_t)t * 768]);
  s *= (1.0f / 64.0f);
  float* dst = isK ? sk : sq;
  dst[((size_t)bh * NBUCK + ib) * 32 + d] = s;
}

// ---------------------------------------------------------------------------
// routing
// ---------------------------------------------------------------------------
__global__ __launch_bounds__(64)
void route_k(const float* __restrict__ sq, const float* __restrict__ sk,
             int* __restrict__ ridx, float* __restrict__ rw) {
  int blk = blockIdx.x;
  int bh = blk >> 7, ib = blk & 127;
  int lane = threadIdx.x;
  const float* qrow = sq + ((size_t)bh * NBUCK + ib) * 32;
  const float* k0 = sk + ((size_t)bh * NBUCK + lane) * 32;
  const float* k1 = k0 + 64 * 32;
  float s0 = 0.f, s1 = 0.f;
#pragma unroll
  for (int d = 0; d < 32; d++) {
    float qd = qrow[d];
    s0 += qd * k0[d];
    s1 += qd * k1[d];
  }
  const float sc = 0.17677669529663687f * (4.0f / 3.0f);
  float L0 = s0 * sc, L1 = s1 * sc;
  float m = fmaxf(L0, L1);
#pragma unroll
  for (int off = 32; off; off >>= 1) m = fmaxf(m, __shfl_xor(m, off));
  float Z = expf(L0 - m) + expf(L1 - m);
#pragma unroll
  for (int off = 32; off; off >>= 1) Z += __shfl_xor(Z, off);
  float mv = (L1 > L0) ? L1 : L0;
  int mj = (L1 > L0) ? lane + 64 : lane;
#pragma unroll
  for (int off = 32; off; off >>= 1) {
    float ov = __shfl_xor(mv, off);
    int oj = __shfl_xor(mj, off);
    if (ov > mv || (ov == mv && oj < mj)) { mv = ov; mj = oj; }
  }
  if (lane == 0) {
    ridx[blk] = mj;
    rw[blk] = 1.0f / Z;
  }
}

// ---------------------------------------------------------------------------
// MFMA bucketed attention reading packed qkv (ld 768). Output bf16.
// ---------------------------------------------------------------------------
__global__ __launch_bounds__(256)
void attn_mfma_k(const ushort* __restrict__ qkv,
                 const int* __restrict__ ridx, const float* __restrict__ rw,
                 ushort* __restrict__ o) {
  __shared__ ushort Qs[64][40];
  __shared__ ushort Ks[128][40];
  __shared__ ushort Vt[32][136];
  __shared__ ushort Ps[4][16][136];
  int blk = blockIdx.x;
  int bh = blk >> 7, ib = blk & 127;
  int b = bh >> 3, h = bh & 7;
  int tid = threadIdx.x;
  int jr = ridx[blk];
  float w = rw[blk];
  {
    int r = tid >> 2, c = (tid & 3) << 3;
    const ushort* src = qkv + ((size_t)b * T_LEN + (size_t)ib * 64 + r) * 768 + h * 32 + c;
    *(bf16x8*)&Qs[r][c] = *(const bf16x8*)src;
  }
#pragma unroll
  for (int p = 0; p < 2; p++) {
    int idx = tid + (p << 8);
    int r = idx >> 2, c = (idx & 3) << 3;
    int srcb = (r < 64) ? jr : ib;
    int tt = r & 63;
    const ushort* src = qkv + ((size_t)b * T_LEN + (size_t)srcb * 64 + tt) * 768 + 256 + h * 32 + c;
    *(bf16x8*)&Ks[r][c] = *(const bf16x8*)src;
  }
  {
    int tok = tid >> 1, d0 = (tid & 1) << 4;
    int srcb = (tok < 64) ? jr : ib;
    int tt = tok & 63;
    const ushort* src = qkv + ((size_t)b * T_LEN + (size_t)srcb * 64 + tt) * 768 + 512 + h * 32 + d0;
    bf16x8 v0 = *(const bf16x8*)src;
    bf16x8 v1 = *(const bf16x8*)(src + 8);
#pragma unroll
    for (int j = 0; j < 8; j++) {
      Vt[d0 + j][tok] = (ushort)v0[j];
      Vt[d0 + 8 + j][tok] = (ushort)v1[j];
    }
  }
  __syncthreads();
  int wid = tid >> 6, lane = tid & 63, l15 = lane & 15, quad = lane >> 4;
  bf16x8 aQ = *(const bf16x8*)&Qs[(wid << 4) + l15][quad << 3];
  f32x4 sf[8];
#pragma unroll
  for (int jn = 0; jn < 8; jn++) {
    bf16x8 bK = *(const bf16x8*)&Ks[(jn << 4) + l15][quad << 3];
    f32x4 z = {0.f, 0.f, 0.f, 0.f};
    sf[jn] = __builtin_amdgcn_mfma_f32_16x16x32_bf16(aQ, bK, z, 0, 0, 0);
  }
  const float sc = 0.17677669529663687f;
#pragma unroll
  for (int jn = 0; jn < 8; jn++) {
    float mult = (jn < 4) ? w * sc : sc;
#pragma unroll
    for (int r = 0; r < 4; r++) sf[jn][r] *= mult;
  }
  float mx[4], sm[4], inv[4];
#pragma unroll
  for (int r = 0; r < 4; r++) {
    float m = sf[0][r];
#pragma unroll
    for (int jn = 1; jn < 8; jn++) m = fmaxf(m, sf[jn][r]);
    mx[r] = m;
  }
#pragma unroll
  for (int off = 1; off < 16; off <<= 1)
#pragma unroll
    for (int r = 0; r < 4; r++) mx[r] = fmaxf(mx[r], __shfl_xor(mx[r], off));
#pragma unroll
  for (int r = 0; r < 4; r++) sm[r] = 0.f;
#pragma unroll
  for (int jn = 0; jn < 8; jn++)
#pragma unroll
    for (int r = 0; r < 4; r++) {
      sf[jn][r] = expf(sf[jn][r] - mx[r]);
      sm[r] += sf[jn][r];
    }
#pragma unroll
  for (int off = 1; off < 16; off <<= 1)
#pragma unroll
    for (int r = 0; r < 4; r++) sm[r] += __shfl_xor(sm[r], off);
#pragma unroll
  for (int r = 0; r < 4; r++) inv[r] = 1.0f / sm[r];
#pragma unroll
  for (int jn = 0; jn < 8; jn++) {
    float ws2 = (jn < 4) ? w : 1.f;
#pragma unroll
    for (int r = 0; r < 4; r++)
      Ps[wid][(quad << 2) + r][(jn << 4) + l15] = f2bf(sf[jn][r] * inv[r] * ws2);
  }
  f32x4 of[2];
#pragma unroll
  for (int nd = 0; nd < 2; nd++) { f32x4 z = {0.f, 0.f, 0.f, 0.f}; of[nd] = z; }
#pragma unroll
  for (int kk = 0; kk < 4; kk++) {
    bf16x8 aP = *(const bf16x8*)&Ps[wid][l15][(kk << 5) + (quad << 3)];
#pragma unroll
    for (int nd = 0; nd < 2; nd++) {
      bf16x8 bV = *(const bf16x8*)&Vt[(nd << 4) + l15][(kk << 5) + (quad << 3)];
      of[nd] = __builtin_amdgcn_mfma_f32_16x16x32_bf16(aP, bV, of[nd], 0, 0, 0);
    }
  }
  ushort* obase = o + ((size_t)b * T_LEN + (size_t)ib * 64 + (wid << 4) + (quad << 2)) * 256 + h * 32 + l15;
#pragma unroll
  for (int nd = 0; nd < 2; nd++)
#pragma unroll
    for (int r = 0; r < 4; r++)
      obase[(size_t)r * 256 + (nd << 4)] = f2bf(of[nd][r]);
}

// ---------------------------------------------------------------------------
// out[b,d,t] = yln[b,t,d]
// ---------------------------------------------------------------------------
__global__ __launch_bounds__(256)
void transpose_out_k(const float* __restrict__ yln, float* __restrict__ out) {
  __shared__ float tile[32][33];
  int b  = blockIdx.z;
  int t0 = blockIdx.x * 32;
  int d0 = blockIdx.y * 32;
  int tx = threadIdx.x;
  int ty = threadIdx.y;
#pragma unroll
  for (int k = 0; k < 4; k++) {
    int t = t0 + ty + k * 8;
    tile[ty + k * 8][tx] = yln[((size_t)b * T_LEN + t) * DIMC + d0 + tx];
  }
  __syncthreads();
#pragma unroll
  for (int k = 0; k < 4; k++) {
    int d = d0 + ty + k * 8;
    out[((size_t)b * DIMC + d) * T_LEN + t0 + tx] = tile[tx][ty + k * 8];
  }
}

// ---------------------------------------------------------------------------
extern "C" void kernel_launch(void* const* d_in, const int* in_sizes, int n_in,
                              void* d_out, int out_size, void* d_ws, size_t ws_size,
                              hipStream_t stream) {
  const float* x     = (const float*)d_in[0];
  const float* pe0   = (const float*)d_in[1];
  const float* pe1   = (const float*)d_in[2];
  const float* ln1_g = (const float*)d_in[3];
  const float* ln1_b = (const float*)d_in[4];
  const float* Wq    = (const float*)d_in[5];
  const float* Wkv   = (const float*)d_in[6];
  const float* Wo    = (const float*)d_in[7];
  const float* bo    = (const float*)d_in[8];
  const float* ln2_g = (const float*)d_in[9];
  const float* ln2_b = (const float*)d_in[10];
  const float* W1    = (const float*)d_in[11];
  const float* b1    = (const float*)d_in[12];
  const float* W2    = (const float*)d_in[13];
  const float* b2    = (const float*)d_in[14];
  const float* gf    = (const float*)d_in[15];
  const float* bfp   = (const float*)d_in[16];
  float* out = (float*)d_out;

  const int M = MROWS;
  float*  y    = (float*)d_ws;                       // M*256 f32
  ushort* qkv  = (ushort*)(y + (size_t)M * 256);     // M*768 bf16
  ushort* bufA = qkv + (size_t)M * 768;              // attn out (bf16)
  ushort* bufB = bufA + (size_t)M * 256;             // LN out (bf16)
  ushort* wbf  = bufB + (size_t)M * 256;             // 6*786432 transposed weights
  float*  sqb  = (float*)(wbf + (size_t)6 * 786432);
  float*  skb  = sqb + 131072;
  float*  rwb  = skb + 131072;
  int*    rib  = (int*)(rwb + 4096);
  ushort* ffbf = qkv;   // FF intermediate (M*1024) overlays dead qkv+bufA

  dim3 tb(32, 8);
  wt_bf16_k<<<dim3(8, 8, 6),  tb, 0, stream>>>(Wq,  wbf + 0,      256, 256,  786432);
  wt_bf16_k<<<dim3(16, 8, 6), tb, 0, stream>>>(Wkv, wbf + 65536,  256, 512,  786432);
  wt_bf16_k<<<dim3(8, 8, 6),  tb, 0, stream>>>(Wo,  wbf + 196608, 256, 256,  786432);
  wt_bf16_k<<<dim3(32, 8, 6), tb, 0, stream>>>(W1,  wbf + 262144, 256, 1024, 786432);
  wt_bf16_k<<<dim3(8, 32, 6), tb, 0, stream>>>(W2,  wbf + 524288, 1024, 256, 786432);

  add_pos_k<<<dim3(T_LEN / 32, DIMC / 32, 4), tb, 0, stream>>>(x, pe0, pe1, y);
  layernorm_k<<<M / 4, 256, 0, stream>>>(y, ln1_g, ln1_b, bufB);   // layer-0 LN1

  for (int l = 0; l < 6; l++) {
    const ushort* wl    = wbf + (size_t)l * 786432;
    const ushort* wqkvT = wl;
    const ushort* woT   = wl + 196608;
    const ushort* w1T   = wl + 262144;
    const ushort* w2T   = wl + 524288;

    gemm_bf16<0><<<dim3(6, M / 128), 256, 0, stream>>>(bufB, wqkvT, nullptr, qkv, 768, 256, 256, 256);
    summary_k<<<BHEAD * NBUCK, 64, 0, stream>>>(qkv, sqb, skb);
    route_k<<<BHEAD * NBUCK, 64, 0, stream>>>(sqb, skb, rib, rwb);
    attn_mfma_k<<<BHEAD * NBUCK, 256, 0, stream>>>(qkv, rib, rwb, bufA);
    // o-proj + bias + residual + LN2 -> bufB (K=256)
    oproj_ln_k<0><<<M / 32, 256, 0, stream>>>(bufA, woT, bo + l * 256, y,
                                              ln2_g + l * 256, ln2_b + l * 256,
                                              bufB, 256, 256);
    // FF1 + gelu -> ffbf (overlays dead qkv+bufA)
    gemm_bf16<1><<<dim3(8, M / 128), 256, 0, stream>>>(bufB, w1T, b1 + l * 1024, ffbf, 1024, 256, 256, 256);
    // FF2 + bias + residual + LN (next LN1 / final LN), K=1024
    if (l < 5) {
      oproj_ln_k<0><<<M / 32, 256, 0, stream>>>(ffbf, w2T, b2 + l * 256, y,
                                                ln1_g + (l + 1) * 256, ln1_b + (l + 1) * 256,
                                                bufB, 1024, 1024);
    } else {
      oproj_ln_k<1><<<M / 32, 256, 0, stream>>>(ffbf, w2T, b2 + l * 256, y,
                                                gf, bfp, nullptr, 1024, 1024);
    }
  }

  transpose_out_k<<<dim3(T_LEN / 32, DIMC / 32, 4), tb, 0, stream>>>(y, out);

  (void)in_sizes; (void)n_in; (void)out_size; (void)ws_size;
}

// Round 8
// 1361.112 us; speedup vs baseline: 4.8037x; 1.0678x over previous
//
#include <hip/hip_runtime.h>
#include <cstdint>
#include <cstddef>

#define T_LEN 8192
#define DIMC  256
#define NBUCK 128
#define BHEAD 32
#define MROWS 32768

typedef __attribute__((ext_vector_type(8))) short bf16x8;
typedef __attribute__((ext_vector_type(4))) float f32x4;

__device__ __forceinline__ ushort f2bf(float x) {
  union { float f; unsigned u; } v; v.f = x;
  unsigned r = v.u + 0x7fffu + ((v.u >> 16) & 1u);
  return (ushort)(r >> 16);
}
__device__ __forceinline__ float bf2f(ushort u) {
  union { unsigned u; float f; } v; v.u = ((unsigned)u) << 16; return v.f;
}

__device__ __forceinline__ void gld16(const void* g, void* l) {
  __builtin_amdgcn_global_load_lds((const __attribute__((address_space(1))) void*)g,
                                   (__attribute__((address_space(3))) void*)l, 16, 0, 0);
}

// gelu with A&S 7.1.26 erf (|err| <= 1.5e-7)
__device__ __forceinline__ float fast_gelu(float v) {
  float x = v * 0.70710678118654752f;
  float ax = fabsf(x);
  float t = 1.0f / fmaf(0.3275911f, ax, 1.0f);
  float poly = t * fmaf(t, fmaf(t, fmaf(t, fmaf(t, 1.061405429f, -1.453152027f),
                                        1.421413741f), -0.284496736f), 0.254829592f);
  float e = __expf(-ax * ax);
  float er = 1.0f - poly * e;
  er = (x < 0.f) ? -er : er;
  return 0.5f * v * (1.0f + er);
}

// ---------------------------------------------------------------------------
// y[b,t,d] = x[b,d,t] + pe0[t/64,d] + pe1[t%64,d]
// ---------------------------------------------------------------------------
__global__ __launch_bounds__(256)
void add_pos_k(const float* __restrict__ x, const float* __restrict__ pe0,
               const float* __restrict__ pe1, float* __restrict__ y) {
  __shared__ float tile[32][33];
  int b  = blockIdx.z;
  int t0 = blockIdx.x * 32;
  int d0 = blockIdx.y * 32;
  int tj = threadIdx.x;
  int di = threadIdx.y;
#pragma unroll
  for (int k = 0; k < 4; k++) {
    int d = d0 + di + k * 8;
    tile[di + k * 8][tj] = x[((size_t)b * DIMC + d) * T_LEN + t0 + tj];
  }
  __syncthreads();
#pragma unroll
  for (int k = 0; k < 4; k++) {
    int t = t0 + di + k * 8;
    int d = d0 + tj;
    y[((size_t)b * T_LEN + t) * DIMC + d] =
        tile[tj][di + k * 8] + pe0[(size_t)(t >> 6) * DIMC + d] + pe1[(size_t)(t & 63) * DIMC + d];
  }
}

// ---------------------------------------------------------------------------
// Standalone LayerNorm (layer-0 LN1 only). Writes bf16.
// ---------------------------------------------------------------------------
__global__ __launch_bounds__(256)
void layernorm_k(const float* __restrict__ x, const float* __restrict__ g,
                 const float* __restrict__ b, ushort* __restrict__ o) {
  int row  = blockIdx.x * 4 + (threadIdx.x >> 6);
  int lane = threadIdx.x & 63;
  const float4* xr = (const float4*)(x + (size_t)row * DIMC);
  float4 v = xr[lane];
  float s  = v.x + v.y + v.z + v.w;
  float s2 = v.x * v.x + v.y * v.y + v.z * v.z + v.w * v.w;
#pragma unroll
  for (int off = 32; off; off >>= 1) {
    s  += __shfl_xor(s, off);
    s2 += __shfl_xor(s2, off);
  }
  float mean = s * (1.0f / 256.0f);
  float var  = s2 * (1.0f / 256.0f) - mean * mean;
  float r    = rsqrtf(var + 1e-5f);
  float4 gv = ((const float4*)g)[lane];
  float4 bv = ((const float4*)b)[lane];
  ushort4 o4;
  o4.x = f2bf((v.x - mean) * r * gv.x + bv.x);
  o4.y = f2bf((v.y - mean) * r * gv.y + bv.y);
  o4.z = f2bf((v.z - mean) * r * gv.z + bv.z);
  o4.w = f2bf((v.w - mean) * r * gv.w + bv.w);
  ((ushort4*)(o + (size_t)row * DIMC))[lane] = o4;
}

// ---------------------------------------------------------------------------
// weight convert: Wt[l][n][k] = bf16(W[l][k][n])
// ---------------------------------------------------------------------------
__global__ __launch_bounds__(256)
void wt_bf16_k(const float* __restrict__ W, ushort* __restrict__ Wt,
               int K, int N, size_t outStride) {
  __shared__ float t[32][33];
  int l = blockIdx.z;
  const float* Wl = W + (size_t)l * K * N;
  ushort* Wtl = Wt + (size_t)l * outStride;
  int n0 = blockIdx.x * 32, k0 = blockIdx.y * 32;
  int tx = threadIdx.x, ty = threadIdx.y;
#pragma unroll
  for (int p = 0; p < 4; p++)
    t[ty + p * 8][tx] = Wl[(size_t)(k0 + ty + p * 8) * N + n0 + tx];
  __syncthreads();
#pragma unroll
  for (int p = 0; p < 4; p++)
    Wtl[(size_t)(n0 + ty + p * 8) * K + k0 + tx] = f2bf(t[tx][ty + p * 8]);
}

// ---------------------------------------------------------------------------
// bf16 MFMA GEMM: epi(A(MxK,lda) @ Bt(NxK,ldb)^T [+bias]) -> bf16
// EPI 0: store. EPI 1: gelu(.+bias).
// Grid: (M/128, N/128) -- bm on x so all column tiles of one bm share an XCD.
// 128x128 tile, BK=32, 256 threads (2x2 waves), 4x4 MFMA per wave.
// Epilogue: per-wave LDS transpose -> bf16x8 coalesced stores.
// ---------------------------------------------------------------------------
template <int EPI>
__global__ __launch_bounds__(256)
void gemm_bf16(const ushort* __restrict__ A, const ushort* __restrict__ Bt,
               const float* __restrict__ bias, ushort* __restrict__ Cbf,
               int N, int K, int lda, int ldb) {
  __shared__ ushort As[128 * 32];
  __shared__ ushort Bs[128 * 32];
  __shared__ ushort eb[4][16][66];   // per-wave transpose buffer (pad 66)
  int tid = threadIdx.x;
  int w = tid >> 6, lane = tid & 63;
  int bm = blockIdx.x << 7, bn = blockIdx.y << 7;
  int wm = (w >> 1) << 6, wn = (w & 1) << 6;
  int l15 = lane & 15, quad = lane >> 4;

  int off0 = (w << 11) + (lane << 4);
  int off1 = off0 + 1024;
  int r0 = off0 >> 6, c0 = (off0 & 63) >> 1;
  int r1 = off1 >> 6, c1 = (off1 & 63) >> 1;
  const ushort* ga0 = A + (size_t)(bm + r0) * lda + c0;
  const ushort* ga1 = A + (size_t)(bm + r1) * lda + c1;
  const ushort* gb0 = Bt + (size_t)(bn + r0) * ldb + c0;
  const ushort* gb1 = Bt + (size_t)(bn + r1) * ldb + c1;
  ushort* lA0 = As + (w << 10);
  ushort* lA1 = lA0 + 512;
  ushort* lB0 = Bs + (w << 10);
  ushort* lB1 = lB0 + 512;

  f32x4 acc[4][4];
#pragma unroll
  for (int i = 0; i < 4; i++)
#pragma unroll
    for (int j = 0; j < 4; j++) {
      f32x4 z = {0.f, 0.f, 0.f, 0.f};
      acc[i][j] = z;
    }

  for (int k0 = 0; k0 < K; k0 += 32) {
    gld16(ga0 + k0, lA0);
    gld16(ga1 + k0, lA1);
    gld16(gb0 + k0, lB0);
    gld16(gb1 + k0, lB1);
    __syncthreads();
    bf16x8 aF[4], bF[4];
#pragma unroll
    for (int i = 0; i < 4; i++)
      aF[i] = *(const bf16x8*)(As + ((wm + (i << 4) + l15) << 5) + (quad << 3));
#pragma unroll
    for (int j = 0; j < 4; j++)
      bF[j] = *(const bf16x8*)(Bs + ((wn + (j << 4) + l15) << 5) + (quad << 3));
#pragma unroll
    for (int i = 0; i < 4; i++)
#pragma unroll
      for (int j = 0; j < 4; j++)
        acc[i][j] = __builtin_amdgcn_mfma_f32_16x16x32_bf16(aF[i], bF[j], acc[i][j], 0, 0, 0);
    __syncthreads();
  }

  float bvj[4];
  if (EPI == 1) {
#pragma unroll
    for (int j = 0; j < 4; j++) bvj[j] = bias[bn + wn + (j << 4) + l15];
  }
#pragma unroll
  for (int i = 0; i < 4; i++) {
    // 16 rows x 64 cols -> per-wave LDS (wave-local, no barrier needed)
#pragma unroll
    for (int j = 0; j < 4; j++) {
#pragma unroll
      for (int r = 0; r < 4; r++) {
        float v = acc[i][j][r];
        if (EPI == 1) v = fast_gelu(v + bvj[j]);
        eb[w][(quad << 2) + r][(j << 4) + l15] = f2bf(v);
      }
    }
#pragma unroll
    for (int h = 0; h < 2; h++) {
      int chunk = (h << 6) + lane;          // 0..127
      int row = chunk >> 3, c8 = (chunk & 7) << 3;
      bf16x8 vv = *(const bf16x8*)&eb[w][row][c8];
      *(bf16x8*)&Cbf[(size_t)(bm + wm + (i << 4) + row) * N + bn + wn + c8] = vv;
    }
  }
}

// ---------------------------------------------------------------------------
// GEMM + bias + residual + LayerNorm. 32-row blocks (grid M/32), 256 threads.
// Waves 2x2: wave = 16 rows x 128 cols. Generic K (multiple of 32).
//   v = A@Bt^T + bias + y
//   FINAL=0: y = v ; obf = bf16(LN(v)) via LDS-transpose vector stores
//   FINAL=1: y = LN(v) (fp32 final)
// ---------------------------------------------------------------------------
template <int FINAL>
__global__ __launch_bounds__(256)
void oproj_ln_k(const ushort* __restrict__ A, const ushort* __restrict__ Bt,
                const float* __restrict__ bias, float* __restrict__ y,
                const float* __restrict__ g, const float* __restrict__ b,
                ushort* __restrict__ obf, int K, int lda) {
  __shared__ ushort smem[32 * 32 + 256 * 32];   // As (2KB) | Bs (16KB)
  __shared__ float red[4][16][2];
  __shared__ float stat[32][2];
  ushort* As = smem;
  ushort* Bs = smem + 32 * 32;
  int tid = threadIdx.x;
  int wid = tid >> 6, lane = tid & 63;
  int l15 = lane & 15, quad = lane >> 4;
  int bm = blockIdx.x << 5;
  int wm = (wid >> 1) << 4;   // 0 / 16
  int wn = (wid & 1) << 7;    // 0 / 128

  int ua = (wid << 6) + lane;
  int ra = ua >> 2, kqa = ua & 3;
  const ushort* gaA = A + (size_t)(bm + ra) * lda + (kqa << 3);
  ushort* lAb = As + (wid << 9);
  const ushort* gaB[4];
  ushort* lBb[4];
#pragma unroll
  for (int p = 0; p < 4; p++) {
    int u = (p << 8) + tid;
    gaB[p] = Bt + (size_t)(u >> 2) * K + ((u & 3) << 3);
    lBb[p] = Bs + ((p << 8) + (wid << 6)) * 8;
  }

  f32x4 acc[8];
#pragma unroll
  for (int j = 0; j < 8; j++) { f32x4 z = {0.f, 0.f, 0.f, 0.f}; acc[j] = z; }

  for (int k0 = 0; k0 < K; k0 += 32) {
    if (wid < 2) gld16(gaA + k0, lAb);
#pragma unroll
    for (int p = 0; p < 4; p++) gld16(gaB[p] + k0, lBb[p]);
    __syncthreads();
    bf16x8 aF = *(const bf16x8*)(As + ((wm + l15) << 5) + (quad << 3));
#pragma unroll
    for (int j = 0; j < 8; j++) {
      bf16x8 bF = *(const bf16x8*)(Bs + ((wn + (j << 4) + l15) << 5) + (quad << 3));
      acc[j] = __builtin_amdgcn_mfma_f32_16x16x32_bf16(aF, bF, acc[j], 0, 0, 0);
    }
    __syncthreads();
  }

  float s1v[4] = {}, s2v[4] = {};
#pragma unroll
  for (int j = 0; j < 8; j++) {
    int col = wn + (j << 4) + l15;
    float bc = bias[col];
#pragma unroll
    for (int r = 0; r < 4; r++) {
      int row = bm + wm + (quad << 2) + r;
      size_t idx = (size_t)row * 256 + col;
      float v = acc[j][r] + bc + y[idx];
      acc[j][r] = v;
      if (!FINAL) y[idx] = v;
      s1v[r] += v;
      s2v[r] += v * v;
    }
  }
#pragma unroll
  for (int off = 1; off < 16; off <<= 1)
#pragma unroll
    for (int r = 0; r < 4; r++) {
      s1v[r] += __shfl_xor(s1v[r], off);
      s2v[r] += __shfl_xor(s2v[r], off);
    }
  if (l15 == 0) {
#pragma unroll
    for (int r = 0; r < 4; r++) {
      red[wid][(quad << 2) + r][0] = s1v[r];
      red[wid][(quad << 2) + r][1] = s2v[r];
    }
  }
  __syncthreads();
  if (tid < 32) {
    int rr = tid;
    float s, s2;
    if (rr < 16) { s = red[0][rr][0] + red[1][rr][0]; s2 = red[0][rr][1] + red[1][rr][1]; }
    else { s = red[2][rr - 16][0] + red[3][rr - 16][0]; s2 = red[2][rr - 16][1] + red[3][rr - 16][1]; }
    float mean = s * (1.0f / 256.0f);
    float var  = s2 * (1.0f / 256.0f) - mean * mean;
    stat[rr][0] = mean;
    stat[rr][1] = rsqrtf(var + 1e-5f);
  }
  __syncthreads();

  if (FINAL) {
#pragma unroll
    for (int j = 0; j < 8; j++) {
      int col = wn + (j << 4) + l15;
      float gc = g[col], bc2 = b[col];
#pragma unroll
      for (int r = 0; r < 4; r++) {
        int lr = wm + (quad << 2) + r;
        float o = (acc[j][r] - stat[lr][0]) * stat[lr][1] * gc + bc2;
        y[(size_t)(bm + lr) * 256 + col] = o;
      }
    }
  } else {
    // LN -> LDS transpose buffer (32 x 266 pad) -> bf16x8 coalesced stores
    ushort (*eb)[266] = (ushort(*)[266])smem;
#pragma unroll
    for (int j = 0; j < 8; j++) {
      int col = wn + (j << 4) + l15;
      float gc = g[col], bc2 = b[col];
#pragma unroll
      for (int r = 0; r < 4; r++) {
        int lr = wm + (quad << 2) + r;
        float o = (acc[j][r] - stat[lr][0]) * stat[lr][1] * gc + bc2;
        eb[lr][col] = f2bf(o);
      }
    }
    __syncthreads();
#pragma unroll
    for (int h = 0; h < 4; h++) {
      int chunk = (h << 8) + tid;           // 0..1023
      int row = chunk >> 5, c8 = (chunk & 31) << 3;
      bf16x8 vv = *(const bf16x8*)&eb[row][c8];
      *(bf16x8*)&obf[(size_t)(bm + row) * 256 + c8] = vv;
    }
  }
}

// ---------------------------------------------------------------------------
// bucket summaries from packed qkv (ld 768): q at +0, k at +256
// ---------------------------------------------------------------------------
__global__ __launch_bounds__(64)
void summary_k(const ushort* __restrict__ qkv,
               float* __restrict__ sq, float* __restrict__ sk) {
  int blk = blockIdx.x;
  int bh = blk >> 7, ib = blk & 127;
  int b = bh >> 3, h = bh & 7;
  int lane = threadIdx.x;
  int d = lane & 31;
  bool isK = lane >= 32;
  size_t base = ((size_t)b * T_LEN + (size_t)ib * 64) * 768 + (isK ? 256 : 0) + h * 32 + d;
  float s = 0.f;
#pragma unroll 8
  for (int t = 0; t < 64; t++) s += bf2f(qkv[base + (size_t)t * 768]);
  s *= (1.0f / 64.0f);
  float* dst = isK ? sk : sq;
  dst[((size_t)bh * NBUCK + ib) * 32 + d] = s;
}

// ---------------------------------------------------------------------------
// routing
// ---------------------------------------------------------------------------
__global__ __launch_bounds__(64)
void route_k(const float* __restrict__ sq, const float* __restrict__ sk,
             int* __restrict__ ridx, float* __restrict__ rw) {
  int blk = blockIdx.x;
  int bh = blk >> 7, ib = blk & 127;
  int lane = threadIdx.x;
  const float* qrow = sq + ((size_t)bh * NBUCK + ib) * 32;
  const float* k0 = sk + ((size_t)bh * NBUCK + lane) * 32;
  const float* k1 = k0 + 64 * 32;
  float s0 = 0.f, s1 = 0.f;
#pragma unroll
  for (int d = 0; d < 32; d++) {
    float qd = qrow[d];
    s0 += qd * k0[d];
    s1 += qd * k1[d];
  }
  const float sc = 0.17677669529663687f * (4.0f / 3.0f);
  float L0 = s0 * sc, L1 = s1 * sc;
  float m = fmaxf(L0, L1);
#pragma unroll
  for (int off = 32; off; off >>= 1) m = fmaxf(m, __shfl_xor(m, off));
  float Z = expf(L0 - m) + expf(L1 - m);
#pragma unroll
  for (int off = 32; off; off >>= 1) Z += __shfl_xor(Z, off);
  float mv = (L1 > L0) ? L1 : L0;
  int mj = (L1 > L0) ? lane + 64 : lane;
#pragma unroll
  for (int off = 32; off; off >>= 1) {
    float ov = __shfl_xor(mv, off);
    int oj = __shfl_xor(mj, off);
    if (ov > mv || (ov == mv && oj < mj)) { mv = ov; mj = oj; }
  }
  if (lane == 0) {
    ridx[blk] = mj;
    rw[blk] = 1.0f / Z;
  }
}

// ---------------------------------------------------------------------------
// MFMA bucketed attention reading packed qkv (ld 768). Output bf16.
// ---------------------------------------------------------------------------
__global__ __launch_bounds__(256)
void attn_mfma_k(const ushort* __restrict__ qkv,
                 const int* __restrict__ ridx, const float* __restrict__ rw,
                 ushort* __restrict__ o) {
  __shared__ ushort Qs[64][40];
  __shared__ ushort Ks[128][40];
  __shared__ ushort Vt[32][136];
  __shared__ ushort Ps[4][16][136];
  int blk = blockIdx.x;
  int bh = blk >> 7, ib = blk & 127;
  int b = bh >> 3, h = bh & 7;
  int tid = threadIdx.x;
  int jr = ridx[blk];
  float w = rw[blk];
  {
    int r = tid >> 2, c = (tid & 3) << 3;
    const ushort* src = qkv + ((size_t)b * T_LEN + (size_t)ib * 64 + r) * 768 + h * 32 + c;
    *(bf16x8*)&Qs[r][c] = *(const bf16x8*)src;
  }
#pragma unroll
  for (int p = 0; p < 2; p++) {
    int idx = tid + (p << 8);
    int r = idx >> 2, c = (idx & 3) << 3;
    int srcb = (r < 64) ? jr : ib;
    int tt = r & 63;
    const ushort* src = qkv + ((size_t)b * T_LEN + (size_t)srcb * 64 + tt) * 768 + 256 + h * 32 + c;
    *(bf16x8*)&Ks[r][c] = *(const bf16x8*)src;
  }
  {
    int tok = tid >> 1, d0 = (tid & 1) << 4;
    int srcb = (tok < 64) ? jr : ib;
    int tt = tok & 63;
    const ushort* src = qkv + ((size_t)b * T_LEN + (size_t)srcb * 64 + tt) * 768 + 512 + h * 32 + d0;
    bf16x8 v0 = *(const bf16x8*)src;
    bf16x8 v1 = *(const bf16x8*)(src + 8);
#pragma unroll
    for (int j = 0; j < 8; j++) {
      Vt[d0 + j][tok] = (ushort)v0[j];
      Vt[d0 + 8 + j][tok] = (ushort)v1[j];
    }
  }
  __syncthreads();
  int wid = tid >> 6, lane = tid & 63, l15 = lane & 15, quad = lane >> 4;
  bf16x8 aQ = *(const bf16x8*)&Qs[(wid << 4) + l15][quad << 3];
  f32x4 sf[8];
#pragma unroll
  for (int jn = 0; jn < 8; jn++) {
    bf16x8 bK = *(const bf16x8*)&Ks[(jn << 4) + l15][quad << 3];
    f32x4 z = {0.f, 0.f, 0.f, 0.f};
    sf[jn] = __builtin_amdgcn_mfma_f32_16x16x32_bf16(aQ, bK, z, 0, 0, 0);
  }
  const float sc = 0.17677669529663687f;
#pragma unroll
  for (int jn = 0; jn < 8; jn++) {
    float mult = (jn < 4) ? w * sc : sc;
#pragma unroll
    for (int r = 0; r < 4; r++) sf[jn][r] *= mult;
  }
  float mx[4], sm[4], inv[4];
#pragma unroll
  for (int r = 0; r < 4; r++) {
    float m = sf[0][r];
#pragma unroll
    for (int jn = 1; jn < 8; jn++) m = fmaxf(m, sf[jn][r]);
    mx[r] = m;
  }
#pragma unroll
  for (int off = 1; off < 16; off <<= 1)
#pragma unroll
    for (int r = 0; r < 4; r++) mx[r] = fmaxf(mx[r], __shfl_xor(mx[r], off));
#pragma unroll
  for (int r = 0; r < 4; r++) sm[r] = 0.f;
#pragma unroll
  for (int jn = 0; jn < 8; jn++)
#pragma unroll
    for (int r = 0; r < 4; r++) {
      sf[jn][r] = expf(sf[jn][r] - mx[r]);
      sm[r] += sf[jn][r];
    }
#pragma unroll
  for (int off = 1; off < 16; off <<= 1)
#pragma unroll
    for (int r = 0; r < 4; r++) sm[r] += __shfl_xor(sm[r], off);
#pragma unroll
  for (int r = 0; r < 4; r++) inv[r] = 1.0f / sm[r];
#pragma unroll
  for (int jn = 0; jn < 8; jn++) {
    float ws2 = (jn < 4) ? w : 1.f;
#pragma unroll
    for (int r = 0; r < 4; r++)
      Ps[wid][(quad << 2) + r][(jn << 4) + l15] = f2bf(sf[jn][r] * inv[r] * ws2);
  }
  f32x4 of[2];
#pragma unroll
  for (int nd = 0; nd < 2; nd++) { f32x4 z = {0.f, 0.f, 0.f, 0.f}; of[nd] = z; }
#pragma unroll
  for (int kk = 0; kk < 4; kk++) {
    bf16x8 aP = *(const bf16x8*)&Ps[wid][l15][(kk << 5) + (quad << 3)];
#pragma unroll
    for (int nd = 0; nd < 2; nd++) {
      bf16x8 bV = *(const bf16x8*)&Vt[(nd << 4) + l15][(kk << 5) + (quad << 3)];
      of[nd] = __builtin_amdgcn_mfma_f32_16x16x32_bf16(aP, bV, of[nd], 0, 0, 0);
    }
  }
  ushort* obase = o + ((size_t)b * T_LEN + (size_t)ib * 64 + (wid << 4) + (quad << 2)) * 256 + h * 32 + l15;
#pragma unroll
  for (int nd = 0; nd < 2; nd++)
#pragma unroll
    for (int r = 0; r < 4; r++)
      obase[(size_t)r * 256 + (nd << 4)] = f2bf(of[nd][r]);
}

// ---------------------------------------------------------------------------
// out[b,d,t] = yln[b,t,d]
// ---------------------------------------------------------------------------
__global__ __launch_bounds__(256)
void transpose_out_k(const float* __restrict__ yln, float* __restrict__ out) {
  __shared__ float tile[32][33];
  int b  = blockIdx.z;
  int t0 = blockIdx.x * 32;
  int d0 = blockIdx.y * 32;
  int tx = threadIdx.x;
  int ty = threadIdx.y;
#pragma unroll
  for (int k = 0; k < 4; k++) {
    int t = t0 + ty + k * 8;
    tile[ty + k * 8][tx] = yln[((size_t)b * T_LEN + t) * DIMC + d0 + tx];
  }
  __syncthreads();
#pragma unroll
  for (int k = 0; k < 4; k++) {
    int d = d0 + ty + k * 8;
    out[((size_t)b * DIMC + d) * T_LEN + t0 + tx] = tile[tx][ty + k * 8];
  }
}

// ---------------------------------------------------------------------------
extern "C" void kernel_launch(void* const* d_in, const int* in_sizes, int n_in,
                              void* d_out, int out_size, void* d_ws, size_t ws_size,
                              hipStream_t stream) {
  const float* x     = (const float*)d_in[0];
  const float* pe0   = (const float*)d_in[1];
  const float* pe1   = (const float*)d_in[2];
  const float* ln1_g = (const float*)d_in[3];
  const float* ln1_b = (const float*)d_in[4];
  const float* Wq    = (const float*)d_in[5];
  const float* Wkv   = (const float*)d_in[6];
  const float* Wo    = (const float*)d_in[7];
  const float* bo    = (const float*)d_in[8];
  const float* ln2_g = (const float*)d_in[9];
  const float* ln2_b = (const float*)d_in[10];
  const float* W1    = (const float*)d_in[11];
  const float* b1    = (const float*)d_in[12];
  const float* W2    = (const float*)d_in[13];
  const float* b2    = (const float*)d_in[14];
  const float* gf    = (const float*)d_in[15];
  const float* bfp   = (const float*)d_in[16];
  float* out = (float*)d_out;

  const int M = MROWS;
  float*  y    = (float*)d_ws;                       // M*256 f32
  ushort* qkv  = (ushort*)(y + (size_t)M * 256);     // M*768 bf16
  ushort* bufA = qkv + (size_t)M * 768;              // attn out (bf16)
  ushort* bufB = bufA + (size_t)M * 256;             // LN out (bf16)
  ushort* wbf  = bufB + (size_t)M * 256;             // 6*786432 transposed weights
  float*  sqb  = (float*)(wbf + (size_t)6 * 786432);
  float*  skb  = sqb + 131072;
  float*  rwb  = skb + 131072;
  int*    rib  = (int*)(rwb + 4096);
  ushort* ffbf = qkv;   // FF intermediate (M*1024) overlays dead qkv+bufA

  dim3 tb(32, 8);
  wt_bf16_k<<<dim3(8, 8, 6),  tb, 0, stream>>>(Wq,  wbf + 0,      256, 256,  786432);
  wt_bf16_k<<<dim3(16, 8, 6), tb, 0, stream>>>(Wkv, wbf + 65536,  256, 512,  786432);
  wt_bf16_k<<<dim3(8, 8, 6),  tb, 0, stream>>>(Wo,  wbf + 196608, 256, 256,  786432);
  wt_bf16_k<<<dim3(32, 8, 6), tb, 0, stream>>>(W1,  wbf + 262144, 256, 1024, 786432);
  wt_bf16_k<<<dim3(8, 32, 6), tb, 0, stream>>>(W2,  wbf + 524288, 1024, 256, 786432);

  add_pos_k<<<dim3(T_LEN / 32, DIMC / 32, 4), tb, 0, stream>>>(x, pe0, pe1, y);
  layernorm_k<<<M / 4, 256, 0, stream>>>(y, ln1_g, ln1_b, bufB);   // layer-0 LN1

  for (int l = 0; l < 6; l++) {
    const ushort* wl    = wbf + (size_t)l * 786432;
    const ushort* wqkvT = wl;
    const ushort* woT   = wl + 196608;
    const ushort* w1T   = wl + 262144;
    const ushort* w2T   = wl + 524288;

    gemm_bf16<0><<<dim3(M / 128, 6), 256, 0, stream>>>(bufB, wqkvT, nullptr, qkv, 768, 256, 256, 256);
    summary_k<<<BHEAD * NBUCK, 64, 0, stream>>>(qkv, sqb, skb);
    route_k<<<BHEAD * NBUCK, 64, 0, stream>>>(sqb, skb, rib, rwb);
    attn_mfma_k<<<BHEAD * NBUCK, 256, 0, stream>>>(qkv, rib, rwb, bufA);
    // o-proj + bias + residual + LN2 -> bufB (K=256)
    oproj_ln_k<0><<<M / 32, 256, 0, stream>>>(bufA, woT, bo + l * 256, y,
                                              ln2_g + l * 256, ln2_b + l * 256,
                                              bufB, 256, 256);
    // FF1 + gelu -> ffbf (overlays dead qkv+bufA)
    gemm_bf16<1><<<dim3(M / 128, 8), 256, 0, stream>>>(bufB, w1T, b1 + l * 1024, ffbf, 1024, 256, 256, 256);
    // FF2 + bias + residual + LN (next LN1 / final LN), K=1024
    if (l < 5) {
      oproj_ln_k<0><<<M / 32, 256, 0, stream>>>(ffbf, w2T, b2 + l * 256, y,
                                                ln1_g + (l + 1) * 256, ln1_b + (l + 1) * 256,
                                                bufB, 1024, 1024);
    } else {
      oproj_ln_k<1><<<M / 32, 256, 0, stream>>>(ffbf, w2T, b2 + l * 256, y,
                                                gf, bfp, nullptr, 1024, 1024);
    }
  }

  transpose_out_k<<<dim3(T_LEN / 32, DIMC / 32, 4), tb, 0, stream>>>(y, out);

  (void)in_sizes; (void)n_in; (void)out_size; (void)ws_size;
}